// Round 2
// baseline (1171.404 us; speedup 1.0000x reference)
//
#include <hip/hip_runtime.h>

// ---------------------------------------------------------------------------
// QMWLNPairwiseAtomClassifier — round 2:
//  * gather-through-matmul + separable attention (round 0/1, exact)
//  * GEMM v2: BM32xBN64xBK20, 128 thr, 4x4 microtile via float4 LDS reads
//  * multi-problem GEMM batching via blockIdx.z (6-way prologue, 4-way final)
// ---------------------------------------------------------------------------

constexpr int cB = 16, cNR = 96, cNG = 64;
constexpr int cAF = 98, cBF = 6;
constexpr int cH = 300, cQM = 160, cMAXNB = 10, cDEPTH = 4;
constexpr int cP = 2048;
constexpr int cF = 2 * cH + cQM;   // 760
constexpr int cD0 = cF + 10;       // 770

constexpr int Mres = cB * cNR;     // 1536
constexpr int Mrg  = cB * cNG;     // 1024

#define GBM 32
#define GBN 64
#define GBK 20
#define GTH 128

struct GArg {
  const float* A; const float* A2; const float* W; const float* W2;
  float* C; int M; int K; int K2; int act;
};
struct GArgs6 { GArg a[6]; };

// C = act(A@W [+ A2@W2]); A:(M,K) row-major, W:(K,N) row-major, N shared.
__global__ __launch_bounds__(GTH) void gemm_multi(GArgs6 ga, int N)
{
  GArg g = ga.a[blockIdx.z];
  int m0 = blockIdx.y * GBM;
  if (m0 >= g.M) return;
  int n0 = blockIdx.x * GBN;
  __shared__ float As[GBK][GBM + 4];   // 20 x 36 (row = 144B, 16B-aligned)
  __shared__ float Bs[GBK][GBN + 4];   // 20 x 68 (row = 272B, 16B-aligned)
  int tid = threadIdx.x;
  int tx = tid & 15, ty = tid >> 4;    // 16 col-groups x 8 row-groups
  float acc[4][4] = {};
  for (int src = 0; src < 2; ++src) {
    const float* Ap = src ? g.A2 : g.A;
    const float* Wp = src ? g.W2 : g.W;
    int Kc = src ? g.K2 : g.K;
    if (!Ap) continue;
    for (int k0 = 0; k0 < Kc; k0 += GBK) {
      for (int t = tid; t < GBM * GBK; t += GTH) {   // 5 iters
        int m = t / GBK, kk = t - m * GBK;
        int gm = m0 + m, gk = k0 + kk;
        As[kk][m] = (gk < Kc) ? Ap[(size_t)gm * Kc + gk] : 0.f;
      }
      for (int t = tid; t < GBK * GBN; t += GTH) {   // 10 iters
        int kk = t >> 6, n = t & 63;
        int gk = k0 + kk, gn = n0 + n;
        Bs[kk][n] = (gk < Kc && gn < N) ? Wp[(size_t)gk * N + gn] : 0.f;
      }
      __syncthreads();
#pragma unroll
      for (int kk = 0; kk < GBK; ++kk) {
        float4 a = *(const float4*)&As[kk][ty * 4];
        float4 b = *(const float4*)&Bs[kk][tx * 4];
        float av[4] = {a.x, a.y, a.z, a.w};
        float bv[4] = {b.x, b.y, b.z, b.w};
#pragma unroll
        for (int i = 0; i < 4; i++)
#pragma unroll
          for (int j = 0; j < 4; j++)
            acc[i][j] = fmaf(av[i], bv[j], acc[i][j]);
      }
      __syncthreads();
    }
  }
#pragma unroll
  for (int i = 0; i < 4; i++) {
    int gm = m0 + ty * 4 + i;
#pragma unroll
    for (int j = 0; j < 4; j++) {
      int gn = n0 + tx * 4 + j;
      if (gn < N) {
        float v = acc[i][j];
        if (g.act) v = fmaxf(v, 0.f);
        g.C[(size_t)gm * N + gn] = v;
      }
    }
  }
}

// nei_label[node,h] = sum_{k<nn} relu(Ra[ga(node,k),h] + Rb[gb(node,k),h])
__global__ __launch_bounds__(320) void nei_label_k(
    const float* __restrict__ Ra, const float* __restrict__ Rb,
    const int* __restrict__ ag, const int* __restrict__ bg,
    const int* __restrict__ nnb, float* __restrict__ out, int Nn)
{
  int node = blockIdx.x;
  int h = threadIdx.x;
  int nn = nnb[node];
  const int* agp = ag + (size_t)node * cMAXNB * 2;
  const int* bgp = bg + (size_t)node * cMAXNB * 2;
  if (h < cH) {
    float s = 0.f;
    for (int k = 0; k < nn; ++k) {
      int ra = agp[2 * k] * Nn + agp[2 * k + 1];
      int rb = bgp[2 * k] * Nn + bgp[2 * k + 1];
      s += fmaxf(Ra[(size_t)ra * cH + h] + Rb[(size_t)rb * cH + h], 0.f);
    }
    out[(size_t)node * cH + h] = s;
  }
}

// kernels[node,h] = (sum_{k<nn} Sa[ga,h]*Sb[gb,h]) * SelfR[node,h] * nmask[node]
__global__ __launch_bounds__(320) void kernels_k(
    const float* __restrict__ Sa, const float* __restrict__ Sb,
    const float* __restrict__ SelfR,
    const int* __restrict__ ag, const int* __restrict__ bg,
    const int* __restrict__ nnb, const float* __restrict__ nmask,
    float* __restrict__ out, int Nn)
{
  int node = blockIdx.x;
  int h = threadIdx.x;
  int nn = nnb[node];
  const int* agp = ag + (size_t)node * cMAXNB * 2;
  const int* bgp = bg + (size_t)node * cMAXNB * 2;
  if (h < cH) {
    float s = 0.f;
    for (int k = 0; k < nn; ++k) {
      int ra = agp[2 * k] * Nn + agp[2 * k + 1];
      int rb = bgp[2 * k] * Nn + bgp[2 * k + 1];
      s += Sa[(size_t)ra * cH + h] * Sb[(size_t)rb * cH + h];
    }
    out[(size_t)node * cH + h] = s * SelfR[(size_t)node * cH + h] * nmask[node];
  }
}

// per (b,i): att_j = sigmoid(sum_n relu(U[b,i,n]+V[b,j,n])*w_s[n]);
// ctx[b,i,:] = sum_j att_j * rgh[b,j,:]
__global__ __launch_bounds__(256) void att_ctx_k(
    const float* __restrict__ U, const float* __restrict__ V,
    const float* __restrict__ att_w, const float* __restrict__ rgh,
    float* __restrict__ ctx)
{
  int row = blockIdx.x;          // b*NR + i
  int b = row / cNR;
  __shared__ float Ur[cH];
  __shared__ float att[cNG];
  int tid = threadIdx.x;
  for (int n = tid; n < cH; n += 256) Ur[n] = U[(size_t)row * cH + n];
  __syncthreads();
  int wave = tid >> 6, lane = tid & 63;
  for (int j = wave; j < cNG; j += 4) {
    const float* Vr = V + (size_t)(b * cNG + j) * cH;
    float s = 0.f;
    for (int n = lane; n < cH; n += 64)
      s += fmaxf(Ur[n] + Vr[n], 0.f) * att_w[n];
    for (int off = 32; off; off >>= 1) s += __shfl_down(s, off);
    if (lane == 0) att[j] = 1.f / (1.f + expf(-s));
  }
  __syncthreads();
  for (int hh = tid; hh < cH; hh += 256) {
    float c = 0.f;
    for (int j = 0; j < cNG; ++j)
      c += att[j] * rgh[(size_t)(b * cNG + j) * cH + hh];
    ctx[(size_t)row * cH + hh] = c;
  }
}

__global__ __launch_bounds__(256) void assemble_h_k(
    const float* __restrict__ kern, const float* __restrict__ ctx,
    const float* __restrict__ qm, float* __restrict__ h)
{
  int node = blockIdx.x;
  for (int c = threadIdx.x; c < cF; c += 256) {
    float v;
    if (c < cH) v = kern[(size_t)node * cH + c];
    else if (c < 2 * cH) v = ctx[(size_t)node * cH + (c - cH)];
    else v = qm[(size_t)node * cQM + (c - 2 * cH)];
    h[(size_t)node * cF + c] = v;
  }
}

// rh = relu(x @ W0), x[p] = concat(h[s,i]+h[s,j], connect[p])
__global__ __launch_bounds__(GTH) void score_gemm_k(
    const float* __restrict__ h, const float* __restrict__ conn,
    const int* __restrict__ cm, const float* __restrict__ W0,
    float* __restrict__ rh)
{
  __shared__ float As[GBK][GBM + 4];
  __shared__ float Bs[GBK][GBN + 4];
  __shared__ int ridx1[GBM], ridx2[GBM];
  int tid = threadIdx.x;
  int tx = tid & 15, ty = tid >> 4;
  int m0 = blockIdx.y * GBM, n0 = blockIdx.x * GBN;
  if (tid < GBM) {
    int p = m0 + tid;
    int s = cm[p * 3 + 0], i = cm[p * 3 + 1], j = cm[p * 3 + 2];
    ridx1[tid] = s * cNR + i;
    ridx2[tid] = s * cNR + j;
  }
  __syncthreads();
  float acc[4][4] = {};
  for (int k0 = 0; k0 < cD0; k0 += GBK) {
    for (int t = tid; t < GBM * GBK; t += GTH) {
      int m = t / GBK, kk = t - m * GBK;
      int gk = k0 + kk, p = m0 + m;
      float v = 0.f;
      if (gk < cF)
        v = h[(size_t)ridx1[m] * cF + gk] + h[(size_t)ridx2[m] * cF + gk];
      else if (gk < cD0)
        v = conn[(size_t)p * 10 + (gk - cF)];
      As[kk][m] = v;
    }
    for (int t = tid; t < GBK * GBN; t += GTH) {
      int kk = t >> 6, n = t & 63;
      int gk = k0 + kk, gn = n0 + n;
      Bs[kk][n] = (gk < cD0 && gn < cD0) ? W0[(size_t)gk * cD0 + gn] : 0.f;
    }
    __syncthreads();
#pragma unroll
    for (int kk = 0; kk < GBK; ++kk) {
      float4 a = *(const float4*)&As[kk][ty * 4];
      float4 b = *(const float4*)&Bs[kk][tx * 4];
      float av[4] = {a.x, a.y, a.z, a.w};
      float bv[4] = {b.x, b.y, b.z, b.w};
#pragma unroll
      for (int i = 0; i < 4; i++)
#pragma unroll
        for (int j = 0; j < 4; j++)
          acc[i][j] = fmaf(av[i], bv[j], acc[i][j]);
    }
    __syncthreads();
  }
#pragma unroll
  for (int i = 0; i < 4; i++) {
    int gm = m0 + ty * 4 + i;
#pragma unroll
    for (int j = 0; j < 4; j++) {
      int gn = n0 + tx * 4 + j;
      if (gn < cD0)
        rh[(size_t)gm * cD0 + gn] = fmaxf(acc[i][j], 0.f);
    }
  }
}

// one wave per p: val = rh[p]·W_score; atomic segment sums
__global__ __launch_bounds__(256) void score_reduce_k(
    const float* __restrict__ rh, const float* __restrict__ Wsc,
    const int* __restrict__ cm, float* __restrict__ segsum,
    float* __restrict__ segcnt)
{
  int p = blockIdx.x * 4 + (threadIdx.x >> 6);
  int lane = threadIdx.x & 63;
  float s = 0.f;
  for (int d = lane; d < cD0; d += 64) s += rh[(size_t)p * cD0 + d] * Wsc[d];
  for (int off = 32; off; off >>= 1) s += __shfl_down(s, off);
  if (lane == 0) {
    atomicAdd(&segsum[cm[p * 3]], s);
    atomicAdd(&segcnt[cm[p * 3]], 1.f);
  }
}

__global__ void finalize_k(const float* __restrict__ segsum,
                           const float* __restrict__ segcnt,
                           float* __restrict__ out)
{
  int b = threadIdx.x;
  if (b < cB) out[b] = segsum[b] / segcnt[b];
}

extern "C" void kernel_launch(void* const* d_in, const int* in_sizes, int n_in,
                              void* d_out, int out_size, void* d_ws, size_t ws_size,
                              hipStream_t stream)
{
  (void)in_sizes; (void)n_in; (void)out_size; (void)ws_size;
  const float* res_atom = (const float*)d_in[0];
  const float* res_bond = (const float*)d_in[1];
  const int*   res_ag   = (const int*)d_in[2];
  const int*   res_bg   = (const int*)d_in[3];
  const int*   res_nnb  = (const int*)d_in[4];
  const float* res_mask = (const float*)d_in[5];
  const float* rg_atom  = (const float*)d_in[6];
  const float* rg_bond  = (const float*)d_in[7];
  const int*   rg_ag    = (const int*)d_in[8];
  const int*   rg_bg    = (const int*)d_in[9];
  const int*   rg_nnb   = (const int*)d_in[10];
  const float* rg_mask  = (const float*)d_in[11];
  const int*   core     = (const int*)d_in[12];
  const float* qm       = (const float*)d_in[13];
  const float* connect  = (const float*)d_in[14];
  const float* rW_atom  = (const float*)d_in[15];
  const float* rW_na    = (const float*)d_in[16];
  const float* rW_nb    = (const float*)d_in[17];
  const float* rW_self  = (const float*)d_in[18];
  const float* rW_U2    = (const float*)d_in[19];
  const float* rW_U1    = (const float*)d_in[20];
  const float* gW_atom  = (const float*)d_in[21];
  const float* gW_na    = (const float*)d_in[22];
  const float* gW_nb    = (const float*)d_in[23];
  const float* gW_self  = (const float*)d_in[24];
  const float* gW_U2    = (const float*)d_in[25];
  const float* gW_U1    = (const float*)d_in[26];
  const float* W_att_h  = (const float*)d_in[27];
  const float* W_att_s  = (const float*)d_in[28];
  const float* W_score0 = (const float*)d_in[29];
  const float* W_score  = (const float*)d_in[30];
  float* out = (float*)d_out;

  float* ws = (float*)d_ws;
  size_t off = 0;
  auto alloc = [&](size_t n) {
    float* p = ws + off;
    off += (n + 63) & ~(size_t)63;
    return p;
  };
  float* afA_r = alloc((size_t)Mres * cH);
  float* afB_r = alloc((size_t)Mres * cH);
  float* Rb_r  = alloc((size_t)Mres * cH);
  float* Sb_r  = alloc((size_t)Mres * cH);
  float* Ra_r  = alloc((size_t)Mres * cH);
  float* nei_r = alloc((size_t)Mres * cH);
  float* kern_r= alloc((size_t)Mres * cH);
  float* afA_g = alloc((size_t)Mrg * cH);
  float* afB_g = alloc((size_t)Mrg * cH);
  float* Rb_g  = alloc((size_t)Mrg * cH);
  float* Sb_g  = alloc((size_t)Mrg * cH);
  float* Ra_g  = alloc((size_t)Mrg * cH);
  float* nei_g = alloc((size_t)Mrg * cH);
  float* kern_g= alloc((size_t)Mrg * cH);
  float* U     = alloc((size_t)Mres * cH);
  float* V     = alloc((size_t)Mrg * cH);
  float* ctx   = alloc((size_t)Mres * cH);
  float* h760  = alloc((size_t)Mres * cF);
  float* rh    = alloc((size_t)cP * cD0);
  float* segsum = alloc(64);            // [0..15] sums, [16..31] counts
  float* segcnt = segsum + 16;

  dim3 blk(GTH);
  const int NCOL = (cH + GBN - 1) / GBN;        // 5
  const int MROW = Mres / GBM;                  // 48

  GArg zero{};
  auto launch = [&](GArgs6& ga, int nprob) {
    dim3 grid(NCOL, MROW, nprob);
    gemm_multi<<<grid, blk, 0, stream>>>(ga, cH);
  };

  // prologue: af0 (relu atom@W_atom), Rb (bond@U2_bot), Sb (relu bond@W_nb)
  {
    GArgs6 ga{{
      {res_atom, nullptr, rW_atom, nullptr, afA_r, Mres, cAF, 0, 1},
      {rg_atom,  nullptr, gW_atom, nullptr, afA_g, Mrg,  cAF, 0, 1},
      {res_bond, nullptr, rW_U2 + (size_t)cH * cH, nullptr, Rb_r, Mres, cBF, 0, 0},
      {rg_bond,  nullptr, gW_U2 + (size_t)cH * cH, nullptr, Rb_g, Mrg,  cBF, 0, 0},
      {res_bond, nullptr, rW_nb, nullptr, Sb_r, Mres, cBF, 0, 1},
      {rg_bond,  nullptr, gW_nb, nullptr, Sb_g, Mrg,  cBF, 0, 1},
    }};
    launch(ga, 6);
  }

  float* af_r = afA_r; float* afo_r = afB_r;
  float* af_g = afA_g; float* afo_g = afB_g;
  for (int t = 0; t < cDEPTH - 1; ++t) {
    {
      GArgs6 ga{{
        {af_r, nullptr, rW_U2, nullptr, Ra_r, Mres, cH, 0, 0},
        {af_g, nullptr, gW_U2, nullptr, Ra_g, Mrg,  cH, 0, 0},
        zero, zero, zero, zero,
      }};
      launch(ga, 2);
    }
    nei_label_k<<<dim3(Mres), dim3(320), 0, stream>>>(Ra_r, Rb_r, res_ag, res_bg, res_nnb, nei_r, cNR);
    nei_label_k<<<dim3(Mrg),  dim3(320), 0, stream>>>(Ra_g, Rb_g, rg_ag, rg_bg, rg_nnb, nei_g, cNG);
    {
      GArgs6 ga{{
        {af_r, nei_r, rW_U1, rW_U1 + (size_t)cH * cH, afo_r, Mres, cH, cH, 1},
        {af_g, nei_g, gW_U1, gW_U1 + (size_t)cH * cH, afo_g, Mrg,  cH, cH, 1},
        zero, zero, zero, zero,
      }};
      launch(ga, 2);
    }
    { float* t1 = af_r; af_r = afo_r; afo_r = t1; }
    { float* t2 = af_g; af_g = afo_g; afo_g = t2; }
  }

  // final iteration: Sa = relu(af@W_na), SelfR = relu(af@W_self)
  {
    GArgs6 ga{{
      {af_r, nullptr, rW_na,   nullptr, Ra_r,  Mres, cH, 0, 1},
      {af_g, nullptr, gW_na,   nullptr, Ra_g,  Mrg,  cH, 0, 1},
      {af_r, nullptr, rW_self, nullptr, nei_r, Mres, cH, 0, 1},
      {af_g, nullptr, gW_self, nullptr, nei_g, Mrg,  cH, 0, 1},
      zero, zero,
    }};
    launch(ga, 4);
  }
  kernels_k<<<dim3(Mres), dim3(320), 0, stream>>>(Ra_r, Sb_r, nei_r, res_ag, res_bg, res_nnb, res_mask, kern_r, cNR);
  kernels_k<<<dim3(Mrg),  dim3(320), 0, stream>>>(Ra_g, Sb_g, nei_g, rg_ag, rg_bg, rg_nnb, rg_mask, kern_g, cNG);

  // U = res_h @ W_att_h ; V = rg_h @ W_att_h
  {
    GArgs6 ga{{
      {kern_r, nullptr, W_att_h, nullptr, U, Mres, cH, 0, 0},
      {kern_g, nullptr, W_att_h, nullptr, V, Mrg,  cH, 0, 0},
      zero, zero, zero, zero,
    }};
    launch(ga, 2);
  }
  att_ctx_k<<<dim3(Mres), dim3(256), 0, stream>>>(U, V, W_att_s, kern_g, ctx);
  assemble_h_k<<<dim3(Mres), dim3(256), 0, stream>>>(kern_r, ctx, qm, h760);

  score_gemm_k<<<dim3((cD0 + GBN - 1) / GBN, cP / GBM), blk, 0, stream>>>(h760, connect, core, W_score0, rh);
  hipMemsetAsync(segsum, 0, 32 * sizeof(float), stream);
  score_reduce_k<<<dim3(cP / 4), dim3(256), 0, stream>>>(rh, W_score, core, segsum, segcnt);
  finalize_k<<<dim3(1), dim3(64), 0, stream>>>(segsum, segcnt, out);
}

// Round 3
// 470.861 us; speedup vs baseline: 2.4878x; 2.4878x over previous
//
#include <hip/hip_runtime.h>

// ---------------------------------------------------------------------------
// QMWLNPairwiseAtomClassifier — round 3:
//  * gather-through-matmul + separable attention (exact, rounds 0-2)
//  * GEMM v3: BM64xBN64xBK16, 256 thr, register-prefetch double-buffered LDS
//    (fetch k+1 into regs -> compute k from LDS -> store regs -> 1 barrier)
//  * fused nei_label / kernels (res+rg in one grid), att_ctx writes h directly
// ---------------------------------------------------------------------------

constexpr int cB = 16, cNR = 96, cNG = 64;
constexpr int cAF = 98, cBF = 6;
constexpr int cH = 300, cQM = 160, cMAXNB = 10, cDEPTH = 4;
constexpr int cP = 2048;
constexpr int cF = 2 * cH + cQM;   // 760
constexpr int cD0 = cF + 10;       // 770

constexpr int Mres = cB * cNR;     // 1536
constexpr int Mrg  = cB * cNG;     // 1024

#define BM 64
#define BN 64
#define BK 16
#define TH 256

struct GArg {
  const float* A; const float* A2; const float* W; const float* W2;
  float* C; int M; int K; int K2; int act;
};
struct GArgs6 { GArg a[6]; };

// C = act(A@W [+ A2@W2]); A:(M,K) row-major, W:(K,N) row-major, N=cH shared.
// Register-prefetch double-buffered pipeline, one barrier per K-tile.
__global__ __launch_bounds__(TH) void gemm_multi(GArgs6 ga, int N)
{
  GArg g = ga.a[blockIdx.z];
  int m0 = blockIdx.y * BM;
  if (m0 >= g.M) return;
  int n0 = blockIdx.x * BN;
  int Kt = g.K + g.K2;
  int nT = (Kt + BK - 1) / BK;

  __shared__ float As[2][BK][BM + 4];   // row 272B (16B aligned)
  __shared__ float Bs[2][BK][BN + 4];

  int tid = threadIdx.x;
  int tx = tid & 15, ty = tid >> 4;
  int am = tid >> 2;            // 0..63  (A row within tile)
  int ak = (tid & 3) * 4;       // 0,4,8,12 (A k within tile)
  int bk = tid >> 4;            // 0..15  (B row within tile)
  int bn = (tid & 15) * 4;      // 0..60  (B col within tile)

  float a_reg[4], b_reg[4];

  auto fetch = [&](int k0) {
    int gm = m0 + am;
    int gk = k0 + ak;
    if (gk + 3 < g.K) {
      float4 v = *(const float4*)&g.A[(size_t)gm * g.K + gk];
      a_reg[0] = v.x; a_reg[1] = v.y; a_reg[2] = v.z; a_reg[3] = v.w;
    } else if (gk >= g.K && gk + 3 < Kt) {
      float4 v = *(const float4*)&g.A2[(size_t)gm * g.K2 + (gk - g.K)];
      a_reg[0] = v.x; a_reg[1] = v.y; a_reg[2] = v.z; a_reg[3] = v.w;
    } else {
#pragma unroll
      for (int j = 0; j < 4; ++j) {
        int k = gk + j;
        float v = 0.f;
        if (k < g.K) v = g.A[(size_t)gm * g.K + k];
        else if (k < Kt) v = g.A2[(size_t)gm * g.K2 + (k - g.K)];
        a_reg[j] = v;
      }
    }
    int gkb = k0 + bk;
    int gn = n0 + bn;
    const float* Wrow = nullptr;
    if (gkb < g.K) Wrow = g.W + (size_t)gkb * N;
    else if (gkb < Kt) Wrow = g.W2 + (size_t)(gkb - g.K) * N;
    if (Wrow && gn + 3 < N) {
      float4 v = *(const float4*)&Wrow[gn];
      b_reg[0] = v.x; b_reg[1] = v.y; b_reg[2] = v.z; b_reg[3] = v.w;
    } else {
#pragma unroll
      for (int j = 0; j < 4; ++j)
        b_reg[j] = (Wrow && gn + j < N) ? Wrow[gn + j] : 0.f;
    }
  };
  auto store = [&](int buf) {
#pragma unroll
    for (int j = 0; j < 4; ++j) As[buf][ak + j][am] = a_reg[j];
    *(float4*)&Bs[buf][bk][bn] = make_float4(b_reg[0], b_reg[1], b_reg[2], b_reg[3]);
  };

  fetch(0);
  store(0);
  __syncthreads();

  float acc[4][4] = {};
  for (int t = 0; t < nT; ++t) {
    if (t + 1 < nT) fetch((t + 1) * BK);
    int cur = t & 1;
#pragma unroll
    for (int kk = 0; kk < BK; ++kk) {
      float4 a = *(const float4*)&As[cur][kk][ty * 4];
      float4 b = *(const float4*)&Bs[cur][kk][tx * 4];
      float av[4] = {a.x, a.y, a.z, a.w};
      float bv[4] = {b.x, b.y, b.z, b.w};
#pragma unroll
      for (int i = 0; i < 4; i++)
#pragma unroll
        for (int j = 0; j < 4; j++)
          acc[i][j] = fmaf(av[i], bv[j], acc[i][j]);
    }
    if (t + 1 < nT) store(cur ^ 1);
    __syncthreads();
  }

#pragma unroll
  for (int i = 0; i < 4; i++) {
    int gm = m0 + ty * 4 + i;
#pragma unroll
    for (int j = 0; j < 4; j++) {
      int gn = n0 + tx * 4 + j;
      if (gn < N) {
        float v = acc[i][j];
        if (g.act) v = fmaxf(v, 0.f);
        g.C[(size_t)gm * N + gn] = v;
      }
    }
  }
}

// fused res+rg: nei_label[node,h] = sum_{k<nn} relu(Ra[ga,h] + Rb[gb,h])
__global__ __launch_bounds__(320) void nei_label2_k(
    const float* __restrict__ RaR, const float* __restrict__ RbR,
    const int* __restrict__ agR, const int* __restrict__ bgR,
    const int* __restrict__ nnbR, float* __restrict__ outR,
    const float* __restrict__ RaG, const float* __restrict__ RbG,
    const int* __restrict__ agG, const int* __restrict__ bgG,
    const int* __restrict__ nnbG, float* __restrict__ outG)
{
  int node = blockIdx.x;
  const float *Ra, *Rb; const int *ag, *bg, *nnb; float* out; int Nn, loc;
  if (node < Mres) { Ra=RaR; Rb=RbR; ag=agR; bg=bgR; nnb=nnbR; out=outR; Nn=cNR; loc=node; }
  else { Ra=RaG; Rb=RbG; ag=agG; bg=bgG; nnb=nnbG; out=outG; Nn=cNG; loc=node-Mres; }
  int h = threadIdx.x;
  int nn = nnb[loc];
  const int* agp = ag + (size_t)loc * cMAXNB * 2;
  const int* bgp = bg + (size_t)loc * cMAXNB * 2;
  if (h < cH) {
    float s = 0.f;
    for (int k = 0; k < nn; ++k) {
      int ra = agp[2 * k] * Nn + agp[2 * k + 1];
      int rb = bgp[2 * k] * Nn + bgp[2 * k + 1];
      s += fmaxf(Ra[(size_t)ra * cH + h] + Rb[(size_t)rb * cH + h], 0.f);
    }
    out[(size_t)loc * cH + h] = s;
  }
}

// fused res+rg: kernels[node,h] = (sum Sa[ga,h]*Sb[gb,h]) * SelfR[node,h] * mask
__global__ __launch_bounds__(320) void kernels2_k(
    const float* __restrict__ SaR, const float* __restrict__ SbR,
    const float* __restrict__ SelfR_R,
    const int* __restrict__ agR, const int* __restrict__ bgR,
    const int* __restrict__ nnbR, const float* __restrict__ maskR,
    float* __restrict__ outR,
    const float* __restrict__ SaG, const float* __restrict__ SbG,
    const float* __restrict__ SelfR_G,
    const int* __restrict__ agG, const int* __restrict__ bgG,
    const int* __restrict__ nnbG, const float* __restrict__ maskG,
    float* __restrict__ outG)
{
  int node = blockIdx.x;
  const float *Sa, *Sb, *Se, *mk; const int *ag, *bg, *nnb; float* out; int Nn, loc;
  if (node < Mres) { Sa=SaR; Sb=SbR; Se=SelfR_R; ag=agR; bg=bgR; nnb=nnbR; mk=maskR; out=outR; Nn=cNR; loc=node; }
  else { Sa=SaG; Sb=SbG; Se=SelfR_G; ag=agG; bg=bgG; nnb=nnbG; mk=maskG; out=outG; Nn=cNG; loc=node-Mres; }
  int h = threadIdx.x;
  int nn = nnb[loc];
  const int* agp = ag + (size_t)loc * cMAXNB * 2;
  const int* bgp = bg + (size_t)loc * cMAXNB * 2;
  if (h < cH) {
    float s = 0.f;
    for (int k = 0; k < nn; ++k) {
      int ra = agp[2 * k] * Nn + agp[2 * k + 1];
      int rb = bgp[2 * k] * Nn + bgp[2 * k + 1];
      s += Sa[(size_t)ra * cH + h] * Sb[(size_t)rb * cH + h];
    }
    out[(size_t)loc * cH + h] = s * Se[(size_t)loc * cH + h] * mk[loc];
  }
}

// per (b,i): att_j = sigmoid(sum_n relu(U+V)*w_s); writes full h row:
// h[row] = [ kern[row] | sum_j att_j*rgh[b,j] | qm[row] ]
__global__ __launch_bounds__(256) void att_ctx_h_k(
    const float* __restrict__ U, const float* __restrict__ V,
    const float* __restrict__ att_w, const float* __restrict__ rgh,
    const float* __restrict__ kern, const float* __restrict__ qm,
    float* __restrict__ h)
{
  int row = blockIdx.x;          // b*NR + i
  int b = row / cNR;
  __shared__ float Ur[cH];
  __shared__ float att[cNG];
  int tid = threadIdx.x;
  for (int n = tid; n < cH; n += 256) Ur[n] = U[(size_t)row * cH + n];
  __syncthreads();
  int wave = tid >> 6, lane = tid & 63;
  for (int j = wave; j < cNG; j += 4) {
    const float* Vr = V + (size_t)(b * cNG + j) * cH;
    float s = 0.f;
    for (int n = lane; n < cH; n += 64)
      s += fmaxf(Ur[n] + Vr[n], 0.f) * att_w[n];
    for (int off = 32; off; off >>= 1) s += __shfl_down(s, off);
    if (lane == 0) att[j] = 1.f / (1.f + expf(-s));
  }
  __syncthreads();
  float* hrow = h + (size_t)row * cF;
  for (int hh = tid; hh < cH; hh += 256) {
    float c = 0.f;
    for (int j = 0; j < cNG; ++j)
      c += att[j] * rgh[(size_t)(b * cNG + j) * cH + hh];
    hrow[cH + hh] = c;
  }
  for (int c0 = tid; c0 < cH; c0 += 256) hrow[c0] = kern[(size_t)row * cH + c0];
  for (int q0 = tid; q0 < cQM; q0 += 256) hrow[2 * cH + q0] = qm[(size_t)row * cQM + q0];
}

// rh = relu(x @ W0), x[p] = concat(h[s,i]+h[s,j], connect[p]); same pipeline.
__global__ __launch_bounds__(TH) void score_gemm_k(
    const float* __restrict__ h, const float* __restrict__ conn,
    const int* __restrict__ cm, const float* __restrict__ W0,
    float* __restrict__ rh)
{
  int m0 = blockIdx.y * BM, n0 = blockIdx.x * BN;
  __shared__ float As[2][BK][BM + 4];
  __shared__ float Bs[2][BK][BN + 4];
  int tid = threadIdx.x;
  int tx = tid & 15, ty = tid >> 4;
  int am = tid >> 2;
  int ak = (tid & 3) * 4;
  int bk = tid >> 4;
  int bn = (tid & 15) * 4;

  int p = m0 + am;
  int s3 = cm[p * 3 + 0];
  int r1 = s3 * cNR + cm[p * 3 + 1];
  int r2 = s3 * cNR + cm[p * 3 + 2];
  const float* h1 = h + (size_t)r1 * cF;
  const float* h2 = h + (size_t)r2 * cF;
  const float* cp = conn + (size_t)p * 10;

  float a_reg[4], b_reg[4];
  const int nT = (cD0 + BK - 1) / BK;   // 49

  auto fetch = [&](int k0) {
    int gk = k0 + ak;
    if (gk + 3 < cF) {
      float4 u = *(const float4*)&h1[gk];
      float4 v = *(const float4*)&h2[gk];
      a_reg[0] = u.x + v.x; a_reg[1] = u.y + v.y;
      a_reg[2] = u.z + v.z; a_reg[3] = u.w + v.w;
    } else {
#pragma unroll
      for (int j = 0; j < 4; ++j) {
        int k = gk + j;
        float v = 0.f;
        if (k < cF) v = h1[k] + h2[k];
        else if (k < cD0) v = cp[k - cF];
        a_reg[j] = v;
      }
    }
    int gkb = k0 + bk;
    int gn = n0 + bn;
    if (gkb < cD0 && gn + 3 < cD0) {
      float4 v = *(const float4*)&W0[(size_t)gkb * cD0 + gn];
      b_reg[0] = v.x; b_reg[1] = v.y; b_reg[2] = v.z; b_reg[3] = v.w;
    } else {
#pragma unroll
      for (int j = 0; j < 4; ++j)
        b_reg[j] = (gkb < cD0 && gn + j < cD0) ? W0[(size_t)gkb * cD0 + gn + j] : 0.f;
    }
  };
  auto store = [&](int buf) {
#pragma unroll
    for (int j = 0; j < 4; ++j) As[buf][ak + j][am] = a_reg[j];
    *(float4*)&Bs[buf][bk][bn] = make_float4(b_reg[0], b_reg[1], b_reg[2], b_reg[3]);
  };

  fetch(0);
  store(0);
  __syncthreads();

  float acc[4][4] = {};
  for (int t = 0; t < nT; ++t) {
    if (t + 1 < nT) fetch((t + 1) * BK);
    int cur = t & 1;
#pragma unroll
    for (int kk = 0; kk < BK; ++kk) {
      float4 a = *(const float4*)&As[cur][kk][ty * 4];
      float4 b = *(const float4*)&Bs[cur][kk][tx * 4];
      float av[4] = {a.x, a.y, a.z, a.w};
      float bv[4] = {b.x, b.y, b.z, b.w};
#pragma unroll
      for (int i = 0; i < 4; i++)
#pragma unroll
        for (int j = 0; j < 4; j++)
          acc[i][j] = fmaf(av[i], bv[j], acc[i][j]);
    }
    if (t + 1 < nT) store(cur ^ 1);
    __syncthreads();
  }

#pragma unroll
  for (int i = 0; i < 4; i++) {
    int gm = m0 + ty * 4 + i;
#pragma unroll
    for (int j = 0; j < 4; j++) {
      int gn = n0 + tx * 4 + j;
      if (gn < cD0)
        rh[(size_t)gm * cD0 + gn] = fmaxf(acc[i][j], 0.f);
    }
  }
}

// one wave per p: val = rh[p]·W_score; atomic segment sums (cnt is fixed 128)
__global__ __launch_bounds__(256) void score_reduce_k(
    const float* __restrict__ rh, const float* __restrict__ Wsc,
    const int* __restrict__ cm, float* __restrict__ segsum)
{
  int p = blockIdx.x * 4 + (threadIdx.x >> 6);
  int lane = threadIdx.x & 63;
  float s = 0.f;
  for (int d = lane; d < cD0; d += 64) s += rh[(size_t)p * cD0 + d] * Wsc[d];
  for (int off = 32; off; off >>= 1) s += __shfl_down(s, off);
  if (lane == 0) atomicAdd(&segsum[cm[p * 3]], s);
}

__global__ void finalize_k(const float* __restrict__ segsum, float* __restrict__ out)
{
  int b = threadIdx.x;
  if (b < cB) out[b] = segsum[b] * (1.f / 128.f);   // each segment has P/B=128 pairs
}

extern "C" void kernel_launch(void* const* d_in, const int* in_sizes, int n_in,
                              void* d_out, int out_size, void* d_ws, size_t ws_size,
                              hipStream_t stream)
{
  (void)in_sizes; (void)n_in; (void)out_size; (void)ws_size;
  const float* res_atom = (const float*)d_in[0];
  const float* res_bond = (const float*)d_in[1];
  const int*   res_ag   = (const int*)d_in[2];
  const int*   res_bg   = (const int*)d_in[3];
  const int*   res_nnb  = (const int*)d_in[4];
  const float* res_mask = (const float*)d_in[5];
  const float* rg_atom  = (const float*)d_in[6];
  const float* rg_bond  = (const float*)d_in[7];
  const int*   rg_ag    = (const int*)d_in[8];
  const int*   rg_bg    = (const int*)d_in[9];
  const int*   rg_nnb   = (const int*)d_in[10];
  const float* rg_mask  = (const float*)d_in[11];
  const int*   core     = (const int*)d_in[12];
  const float* qm       = (const float*)d_in[13];
  const float* connect  = (const float*)d_in[14];
  const float* rW_atom  = (const float*)d_in[15];
  const float* rW_na    = (const float*)d_in[16];
  const float* rW_nb    = (const float*)d_in[17];
  const float* rW_self  = (const float*)d_in[18];
  const float* rW_U2    = (const float*)d_in[19];
  const float* rW_U1    = (const float*)d_in[20];
  const float* gW_atom  = (const float*)d_in[21];
  const float* gW_na    = (const float*)d_in[22];
  const float* gW_nb    = (const float*)d_in[23];
  const float* gW_self  = (const float*)d_in[24];
  const float* gW_U2    = (const float*)d_in[25];
  const float* gW_U1    = (const float*)d_in[26];
  const float* W_att_h  = (const float*)d_in[27];
  const float* W_att_s  = (const float*)d_in[28];
  const float* W_score0 = (const float*)d_in[29];
  const float* W_score  = (const float*)d_in[30];
  float* out = (float*)d_out;

  float* ws = (float*)d_ws;
  size_t off = 0;
  auto alloc = [&](size_t n) {
    float* p = ws + off;
    off += (n + 63) & ~(size_t)63;
    return p;
  };
  float* afA_r = alloc((size_t)Mres * cH);
  float* afB_r = alloc((size_t)Mres * cH);
  float* Rb_r  = alloc((size_t)Mres * cH);
  float* Sb_r  = alloc((size_t)Mres * cH);
  float* Ra_r  = alloc((size_t)Mres * cH);
  float* nei_r = alloc((size_t)Mres * cH);
  float* kern_r= alloc((size_t)Mres * cH);
  float* afA_g = alloc((size_t)Mrg * cH);
  float* afB_g = alloc((size_t)Mrg * cH);
  float* Rb_g  = alloc((size_t)Mrg * cH);
  float* Sb_g  = alloc((size_t)Mrg * cH);
  float* Ra_g  = alloc((size_t)Mrg * cH);
  float* nei_g = alloc((size_t)Mrg * cH);
  float* kern_g= alloc((size_t)Mrg * cH);
  float* U     = alloc((size_t)Mres * cH);
  float* V     = alloc((size_t)Mrg * cH);
  float* h760  = alloc((size_t)Mres * cF);
  float* rh    = alloc((size_t)cP * cD0);
  float* segsum = alloc(64);

  dim3 blk(TH);
  const int NCOL = (cH + BN - 1) / BN;        // 5
  const int MROW = Mres / BM;                 // 24

  GArg zero{};
  auto launch = [&](GArgs6& ga, int nprob) {
    dim3 grid(NCOL, MROW, nprob);
    gemm_multi<<<grid, blk, 0, stream>>>(ga, cH);
  };

  // prologue: af0 (relu atom@W_atom), Rb (bond@U2_bot), Sb (relu bond@W_nb)
  {
    GArgs6 ga{{
      {res_atom, nullptr, rW_atom, nullptr, afA_r, Mres, cAF, 0, 1},
      {rg_atom,  nullptr, gW_atom, nullptr, afA_g, Mrg,  cAF, 0, 1},
      {res_bond, nullptr, rW_U2 + (size_t)cH * cH, nullptr, Rb_r, Mres, cBF, 0, 0},
      {rg_bond,  nullptr, gW_U2 + (size_t)cH * cH, nullptr, Rb_g, Mrg,  cBF, 0, 0},
      {res_bond, nullptr, rW_nb, nullptr, Sb_r, Mres, cBF, 0, 1},
      {rg_bond,  nullptr, gW_nb, nullptr, Sb_g, Mrg,  cBF, 0, 1},
    }};
    launch(ga, 6);
  }

  float* af_r = afA_r; float* afo_r = afB_r;
  float* af_g = afA_g; float* afo_g = afB_g;
  for (int t = 0; t < cDEPTH - 1; ++t) {
    {
      GArgs6 ga{{
        {af_r, nullptr, rW_U2, nullptr, Ra_r, Mres, cH, 0, 0},
        {af_g, nullptr, gW_U2, nullptr, Ra_g, Mrg,  cH, 0, 0},
        zero, zero, zero, zero,
      }};
      launch(ga, 2);
    }
    nei_label2_k<<<dim3(Mres + Mrg), dim3(320), 0, stream>>>(
        Ra_r, Rb_r, res_ag, res_bg, res_nnb, nei_r,
        Ra_g, Rb_g, rg_ag, rg_bg, rg_nnb, nei_g);
    {
      GArgs6 ga{{
        {af_r, nei_r, rW_U1, rW_U1 + (size_t)cH * cH, afo_r, Mres, cH, cH, 1},
        {af_g, nei_g, gW_U1, gW_U1 + (size_t)cH * cH, afo_g, Mrg,  cH, cH, 1},
        zero, zero, zero, zero,
      }};
      launch(ga, 2);
    }
    { float* t1 = af_r; af_r = afo_r; afo_r = t1; }
    { float* t2 = af_g; af_g = afo_g; afo_g = t2; }
  }

  // final iteration: Sa = relu(af@W_na), SelfR = relu(af@W_self)
  {
    GArgs6 ga{{
      {af_r, nullptr, rW_na,   nullptr, Ra_r,  Mres, cH, 0, 1},
      {af_g, nullptr, gW_na,   nullptr, Ra_g,  Mrg,  cH, 0, 1},
      {af_r, nullptr, rW_self, nullptr, nei_r, Mres, cH, 0, 1},
      {af_g, nullptr, gW_self, nullptr, nei_g, Mrg,  cH, 0, 1},
      zero, zero,
    }};
    launch(ga, 4);
  }
  kernels2_k<<<dim3(Mres + Mrg), dim3(320), 0, stream>>>(
      Ra_r, Sb_r, nei_r, res_ag, res_bg, res_nnb, res_mask, kern_r,
      Ra_g, Sb_g, nei_g, rg_ag, rg_bg, rg_nnb, rg_mask, kern_g);

  // U = res_h @ W_att_h ; V = rg_h @ W_att_h
  {
    GArgs6 ga{{
      {kern_r, nullptr, W_att_h, nullptr, U, Mres, cH, 0, 0},
      {kern_g, nullptr, W_att_h, nullptr, V, Mrg,  cH, 0, 0},
      zero, zero, zero, zero,
    }};
    launch(ga, 2);
  }
  att_ctx_h_k<<<dim3(Mres), dim3(256), 0, stream>>>(U, V, W_att_s, kern_g, kern_r, qm, h760);

  score_gemm_k<<<dim3((cD0 + BN - 1) / BN, cP / BM), blk, 0, stream>>>(h760, connect, core, W_score0, rh);
  hipMemsetAsync(segsum, 0, 16 * sizeof(float), stream);
  score_reduce_k<<<dim3(cP / 4), dim3(256), 0, stream>>>(rh, W_score, core, segsum);
  finalize_k<<<dim3(1), dim3(64), 0, stream>>>(segsum, out);
}

// Round 4
// 280.832 us; speedup vs baseline: 4.1712x; 1.6767x over previous
//
#include <hip/hip_runtime.h>

// ---------------------------------------------------------------------------
// QMWLNPairwiseAtomClassifier — round 4:
//  * all GEMMs moved to MFMA via split-bf16 (hi/lo, 3-product) — ~fp32 accuracy
//  * weight prep kernel: transpose + bf16 split + K-pad to 32 (no B bounds)
//  * score GEMM fuses rh·W_score + segment atomic sums into epilogue
// ---------------------------------------------------------------------------

constexpr int cB = 16, cNR = 96, cNG = 64;
constexpr int cAF = 98, cBF = 6;
constexpr int cH = 300, cQM = 160, cMAXNB = 10, cDEPTH = 4;
constexpr int cP = 2048;
constexpr int cF = 2 * cH + cQM;   // 760
constexpr int cD0 = cF + 10;       // 770

constexpr int Mres = cB * cNR;     // 1536
constexpr int Mrg  = cB * cNG;     // 1024

typedef __attribute__((ext_vector_type(8))) short v8s;
typedef __attribute__((ext_vector_type(4))) float v4f;

__device__ inline unsigned short f2bf(float f) {
  unsigned u = __float_as_uint(f);
  u += 0x7FFF + ((u >> 16) & 1);          // RNE
  return (unsigned short)(u >> 16);
}
__device__ inline float bf2f(unsigned short s) {
  return __uint_as_float(((unsigned)s) << 16);
}

// ---------------- weight prep: W[K][N] f32 -> hiT/loT [N][Kpad] bf16 --------
struct PrepArg { const float* W; unsigned short* hiT; unsigned short* loT; int K; int N; int Kpad; };
struct PrepArgs { PrepArg a[16]; };

__global__ __launch_bounds__(256) void prep_k(PrepArgs pa)
{
  PrepArg p = pa.a[blockIdx.z];
  int idx = blockIdx.x * 256 + threadIdx.x;
  int total = p.N * p.Kpad;
  if (idx >= total) return;
  int n = idx / p.Kpad, k = idx - n * p.Kpad;
  float w = (k < p.K) ? p.W[(size_t)k * p.N + n] : 0.f;
  unsigned short h = f2bf(w);
  p.hiT[idx] = h;
  p.loT[idx] = f2bf(w - bf2f(h));
}

// ---------------- MFMA GEMM: C = act(A@W1 [+ A2@W2]) ------------------------
struct GArg {
  const float* A; const float* A2;
  const unsigned short* W1h; const unsigned short* W1l;
  const unsigned short* W2h; const unsigned short* W2l;
  float* C; int M; int K1; int Kp1; int K2; int Kp2; int act;
};
struct GArgs6 { GArg a[6]; };

#define MFMA __builtin_amdgcn_mfma_f32_16x16x32_bf16

__global__ __launch_bounds__(256) void gemm_mfma(GArgs6 ga, int N)
{
  GArg g = ga.a[blockIdx.z];
  int m0 = blockIdx.y * 64;
  if (m0 >= g.M) return;
  int n0 = blockIdx.x * 64;
  int nT = (g.Kp1 + g.Kp2) >> 5;

  __shared__ unsigned short Ah[2][64][40];   // 80B rows: 2-way-only bank alias
  __shared__ unsigned short Al[2][64][40];
  __shared__ unsigned short Bh[2][64][40];
  __shared__ unsigned short Bl[2][64][40];

  int tid = threadIdx.x;
  int sm = tid >> 2;            // staging row (A-m / B-n)
  int sk = (tid & 3) << 3;      // staging k offset (0,8,16,24)

  float areg[8];
  uint4 bh_reg, bl_reg;

  auto fetch = [&](int kv0) {
    int kv = kv0 + sk;
    // A (f32, split later)
    const float* src; int kk, Klim;
    if (kv < g.Kp1) { src = g.A  + (size_t)(m0 + sm) * g.K1; kk = kv;          Klim = g.K1; }
    else            { src = g.A2 + (size_t)(m0 + sm) * g.K2; kk = kv - g.Kp1;  Klim = g.K2; }
    if (((Klim & 3) == 0) && kk + 7 < Klim) {
      float4 v0 = *(const float4*)(src + kk);
      float4 v1 = *(const float4*)(src + kk + 4);
      areg[0]=v0.x; areg[1]=v0.y; areg[2]=v0.z; areg[3]=v0.w;
      areg[4]=v1.x; areg[5]=v1.y; areg[6]=v1.z; areg[7]=v1.w;
    } else {
#pragma unroll
      for (int j = 0; j < 8; ++j) areg[j] = (kk + j < Klim) ? src[kk + j] : 0.f;
    }
    // B (pre-split transposed bf16, K-padded: no k bounds needed)
    int gn = n0 + sm;
    if (gn < N) {
      const unsigned short *ph, *pl;
      if (kv < g.Kp1) { size_t o = (size_t)gn * g.Kp1 + kv;            ph = g.W1h + o; pl = g.W1l + o; }
      else            { size_t o = (size_t)gn * g.Kp2 + (kv - g.Kp1);  ph = g.W2h + o; pl = g.W2l + o; }
      bh_reg = *(const uint4*)ph;
      bl_reg = *(const uint4*)pl;
    } else {
      bh_reg = make_uint4(0,0,0,0); bl_reg = make_uint4(0,0,0,0);
    }
  };

  auto store = [&](int buf) {
    unsigned hs[8], ls[8];
#pragma unroll
    for (int j = 0; j < 8; ++j) {
      unsigned short h = f2bf(areg[j]);
      hs[j] = h;
      ls[j] = f2bf(areg[j] - bf2f(h));
    }
    uint4 hh, ll;
    hh.x = hs[0] | (hs[1] << 16); hh.y = hs[2] | (hs[3] << 16);
    hh.z = hs[4] | (hs[5] << 16); hh.w = hs[6] | (hs[7] << 16);
    ll.x = ls[0] | (ls[1] << 16); ll.y = ls[2] | (ls[3] << 16);
    ll.z = ls[4] | (ls[5] << 16); ll.w = ls[6] | (ls[7] << 16);
    *(uint4*)&Ah[buf][sm][sk] = hh;
    *(uint4*)&Al[buf][sm][sk] = ll;
    *(uint4*)&Bh[buf][sm][sk] = bh_reg;
    *(uint4*)&Bl[buf][sm][sk] = bl_reg;
  };

  int l = tid & 63, w = tid >> 6;
  int wm = (w >> 1) << 5, wn = (w & 1) << 5;     // 2x2 wave grid, 32x32 each
  int ar = wm + (l & 15), br = wn + (l & 15);
  int kc = (l >> 4) << 3;

  v4f acc00 = {0,0,0,0}, acc01 = {0,0,0,0}, acc10 = {0,0,0,0}, acc11 = {0,0,0,0};

  fetch(0); store(0); __syncthreads();
  for (int t = 0; t < nT; ++t) {
    if (t + 1 < nT) fetch((t + 1) << 5);
    int cur = t & 1;
    v8s ah0 = *(const v8s*)&Ah[cur][ar][kc];
    v8s ah1 = *(const v8s*)&Ah[cur][ar + 16][kc];
    v8s al0 = *(const v8s*)&Al[cur][ar][kc];
    v8s al1 = *(const v8s*)&Al[cur][ar + 16][kc];
    v8s bh0 = *(const v8s*)&Bh[cur][br][kc];
    v8s bh1 = *(const v8s*)&Bh[cur][br + 16][kc];
    v8s bl0 = *(const v8s*)&Bl[cur][br][kc];
    v8s bl1 = *(const v8s*)&Bl[cur][br + 16][kc];
    acc00 = MFMA(ah0, bh0, acc00, 0, 0, 0);
    acc00 = MFMA(ah0, bl0, acc00, 0, 0, 0);
    acc00 = MFMA(al0, bh0, acc00, 0, 0, 0);
    acc01 = MFMA(ah0, bh1, acc01, 0, 0, 0);
    acc01 = MFMA(ah0, bl1, acc01, 0, 0, 0);
    acc01 = MFMA(al0, bh1, acc01, 0, 0, 0);
    acc10 = MFMA(ah1, bh0, acc10, 0, 0, 0);
    acc10 = MFMA(ah1, bl0, acc10, 0, 0, 0);
    acc10 = MFMA(al1, bh0, acc10, 0, 0, 0);
    acc11 = MFMA(ah1, bh1, acc11, 0, 0, 0);
    acc11 = MFMA(ah1, bl1, acc11, 0, 0, 0);
    acc11 = MFMA(al1, bh1, acc11, 0, 0, 0);
    if (t + 1 < nT) store(cur ^ 1);
    __syncthreads();
  }

  int rbase = m0 + wm + ((l >> 4) << 2);
  int cbase = n0 + wn + (l & 15);
  auto wr = [&](v4f a, int fi, int fj) {
    int gn = cbase + fj * 16;
    if (gn >= N) return;
    float* Cp = g.C + (size_t)(rbase + fi * 16) * N + gn;
#pragma unroll
    for (int r = 0; r < 4; ++r) {
      float v = a[r];
      if (g.act) v = fmaxf(v, 0.f);
      Cp[(size_t)r * N] = v;
    }
  };
  wr(acc00, 0, 0); wr(acc01, 0, 1); wr(acc10, 1, 0); wr(acc11, 1, 1);
}

// ---------------- score GEMM (gathered A) + fused rh·Wsc segment sums -------
__global__ __launch_bounds__(256) void score_mfma_k(
    const float* __restrict__ h, const float* __restrict__ conn,
    const int* __restrict__ cm,
    const unsigned short* __restrict__ W0h, const unsigned short* __restrict__ W0l,
    const float* __restrict__ Wsc, float* __restrict__ pairsum)
{
  const int Kp = 800;               // roundup(770,32)
  const int nT = Kp >> 5;           // 25
  int m0 = blockIdx.y * 64;
  int n0 = blockIdx.x * 64;

  __shared__ unsigned short Ah[2][64][40];
  __shared__ unsigned short Al[2][64][40];
  __shared__ unsigned short Bh[2][64][40];
  __shared__ unsigned short Bl[2][64][40];

  int tid = threadIdx.x;
  int sm = tid >> 2;
  int sk = (tid & 3) << 3;

  int p = m0 + sm;
  int s3 = cm[p * 3 + 0];
  const float* h1 = h + (size_t)(s3 * cNR + cm[p * 3 + 1]) * cF;
  const float* h2 = h + (size_t)(s3 * cNR + cm[p * 3 + 2]) * cF;
  const float* cp = conn + (size_t)p * 10;

  float areg[8];
  uint4 bh_reg, bl_reg;

  auto fetch = [&](int kv0) {
    int kv = kv0 + sk;
    if (kv + 7 < cF) {
      float4 u = *(const float4*)(h1 + kv);
      float4 v = *(const float4*)(h2 + kv);
      float4 u2 = *(const float4*)(h1 + kv + 4);
      float4 v2 = *(const float4*)(h2 + kv + 4);
      areg[0]=u.x+v.x; areg[1]=u.y+v.y; areg[2]=u.z+v.z; areg[3]=u.w+v.w;
      areg[4]=u2.x+v2.x; areg[5]=u2.y+v2.y; areg[6]=u2.z+v2.z; areg[7]=u2.w+v2.w;
    } else {
#pragma unroll
      for (int j = 0; j < 8; ++j) {
        int k = kv + j;
        float v = 0.f;
        if (k < cF) v = h1[k] + h2[k];
        else if (k < cD0) v = cp[k - cF];
        areg[j] = v;
      }
    }
    int gn = n0 + sm;
    if (gn < cD0) {
      size_t o = (size_t)gn * Kp + kv;
      bh_reg = *(const uint4*)(W0h + o);
      bl_reg = *(const uint4*)(W0l + o);
    } else {
      bh_reg = make_uint4(0,0,0,0); bl_reg = make_uint4(0,0,0,0);
    }
  };

  auto store = [&](int buf) {
    unsigned hs[8], ls[8];
#pragma unroll
    for (int j = 0; j < 8; ++j) {
      unsigned short hv = f2bf(areg[j]);
      hs[j] = hv;
      ls[j] = f2bf(areg[j] - bf2f(hv));
    }
    uint4 hh, ll;
    hh.x = hs[0] | (hs[1] << 16); hh.y = hs[2] | (hs[3] << 16);
    hh.z = hs[4] | (hs[5] << 16); hh.w = hs[6] | (hs[7] << 16);
    ll.x = ls[0] | (ls[1] << 16); ll.y = ls[2] | (ls[3] << 16);
    ll.z = ls[4] | (ls[5] << 16); ll.w = ls[6] | (ls[7] << 16);
    *(uint4*)&Ah[buf][sm][sk] = hh;
    *(uint4*)&Al[buf][sm][sk] = ll;
    *(uint4*)&Bh[buf][sm][sk] = bh_reg;
    *(uint4*)&Bl[buf][sm][sk] = bl_reg;
  };

  int l = tid & 63, w = tid >> 6;
  int wm = (w >> 1) << 5, wn = (w & 1) << 5;
  int ar = wm + (l & 15), br = wn + (l & 15);
  int kc = (l >> 4) << 3;

  v4f acc00 = {0,0,0,0}, acc01 = {0,0,0,0}, acc10 = {0,0,0,0}, acc11 = {0,0,0,0};

  fetch(0); store(0); __syncthreads();
  for (int t = 0; t < nT; ++t) {
    if (t + 1 < nT) fetch((t + 1) << 5);
    int cur = t & 1;
    v8s ah0 = *(const v8s*)&Ah[cur][ar][kc];
    v8s ah1 = *(const v8s*)&Ah[cur][ar + 16][kc];
    v8s al0 = *(const v8s*)&Al[cur][ar][kc];
    v8s al1 = *(const v8s*)&Al[cur][ar + 16][kc];
    v8s bh0 = *(const v8s*)&Bh[cur][br][kc];
    v8s bh1 = *(const v8s*)&Bh[cur][br + 16][kc];
    v8s bl0 = *(const v8s*)&Bl[cur][br][kc];
    v8s bl1 = *(const v8s*)&Bl[cur][br + 16][kc];
    acc00 = MFMA(ah0, bh0, acc00, 0, 0, 0);
    acc00 = MFMA(ah0, bl0, acc00, 0, 0, 0);
    acc00 = MFMA(al0, bh0, acc00, 0, 0, 0);
    acc01 = MFMA(ah0, bh1, acc01, 0, 0, 0);
    acc01 = MFMA(ah0, bl1, acc01, 0, 0, 0);
    acc01 = MFMA(al0, bh1, acc01, 0, 0, 0);
    acc10 = MFMA(ah1, bh0, acc10, 0, 0, 0);
    acc10 = MFMA(ah1, bl0, acc10, 0, 0, 0);
    acc10 = MFMA(al1, bh0, acc10, 0, 0, 0);
    acc11 = MFMA(ah1, bh1, acc11, 0, 0, 0);
    acc11 = MFMA(ah1, bl1, acc11, 0, 0, 0);
    acc11 = MFMA(al1, bh1, acc11, 0, 0, 0);
    if (t + 1 < nT) store(cur ^ 1);
    __syncthreads();
  }

  // fused epilogue: relu + dot with W_score cols of this tile, reduce 16 lanes
  int cbase = n0 + wn + (l & 15);
  float w0 = (cbase      < cD0) ? Wsc[cbase]      : 0.f;
  float w1 = (cbase + 16 < cD0) ? Wsc[cbase + 16] : 0.f;
  float ps[8];
#pragma unroll
  for (int r = 0; r < 4; ++r) {
    ps[r]     = fmaxf(acc00[r], 0.f) * w0 + fmaxf(acc01[r], 0.f) * w1;
    ps[4 + r] = fmaxf(acc10[r], 0.f) * w0 + fmaxf(acc11[r], 0.f) * w1;
  }
#pragma unroll
  for (int m = 1; m < 16; m <<= 1) {
#pragma unroll
    for (int q = 0; q < 8; ++q) ps[q] += __shfl_xor(ps[q], m, 64);
  }
  if ((l & 15) == 0) {
#pragma unroll
    for (int q = 0; q < 8; ++q) {
      int gm = m0 + wm + (q >> 2) * 16 + ((l >> 4) << 2) + (q & 3);
      atomicAdd(&pairsum[gm], ps[q]);
    }
  }
}

// ---------------- gathers / attention (unchanged, exact f32) ----------------
__global__ __launch_bounds__(320) void nei_label2_k(
    const float* __restrict__ RaR, const float* __restrict__ RbR,
    const int* __restrict__ agR, const int* __restrict__ bgR,
    const int* __restrict__ nnbR, float* __restrict__ outR,
    const float* __restrict__ RaG, const float* __restrict__ RbG,
    const int* __restrict__ agG, const int* __restrict__ bgG,
    const int* __restrict__ nnbG, float* __restrict__ outG)
{
  int node = blockIdx.x;
  const float *Ra, *Rb; const int *ag, *bg, *nnb; float* out; int Nn, loc;
  if (node < Mres) { Ra=RaR; Rb=RbR; ag=agR; bg=bgR; nnb=nnbR; out=outR; Nn=cNR; loc=node; }
  else { Ra=RaG; Rb=RbG; ag=agG; bg=bgG; nnb=nnbG; out=outG; Nn=cNG; loc=node-Mres; }
  int h = threadIdx.x;
  int nn = nnb[loc];
  const int* agp = ag + (size_t)loc * cMAXNB * 2;
  const int* bgp = bg + (size_t)loc * cMAXNB * 2;
  if (h < cH) {
    float s = 0.f;
    for (int k = 0; k < nn; ++k) {
      int ra = agp[2 * k] * Nn + agp[2 * k + 1];
      int rb = bgp[2 * k] * Nn + bgp[2 * k + 1];
      s += fmaxf(Ra[(size_t)ra * cH + h] + Rb[(size_t)rb * cH + h], 0.f);
    }
    out[(size_t)loc * cH + h] = s;
  }
}

__global__ __launch_bounds__(320) void kernels2_k(
    const float* __restrict__ SaR, const float* __restrict__ SbR,
    const float* __restrict__ SelfR_R,
    const int* __restrict__ agR, const int* __restrict__ bgR,
    const int* __restrict__ nnbR, const float* __restrict__ maskR,
    float* __restrict__ outR,
    const float* __restrict__ SaG, const float* __restrict__ SbG,
    const float* __restrict__ SelfR_G,
    const int* __restrict__ agG, const int* __restrict__ bgG,
    const int* __restrict__ nnbG, const float* __restrict__ maskG,
    float* __restrict__ outG)
{
  int node = blockIdx.x;
  const float *Sa, *Sb, *Se, *mk; const int *ag, *bg, *nnb; float* out; int Nn, loc;
  if (node < Mres) { Sa=SaR; Sb=SbR; Se=SelfR_R; ag=agR; bg=bgR; nnb=nnbR; mk=maskR; out=outR; Nn=cNR; loc=node; }
  else { Sa=SaG; Sb=SbG; Se=SelfR_G; ag=agG; bg=bgG; nnb=nnbG; mk=maskG; out=outG; Nn=cNG; loc=node-Mres; }
  int h = threadIdx.x;
  int nn = nnb[loc];
  const int* agp = ag + (size_t)loc * cMAXNB * 2;
  const int* bgp = bg + (size_t)loc * cMAXNB * 2;
  if (h < cH) {
    float s = 0.f;
    for (int k = 0; k < nn; ++k) {
      int ra = agp[2 * k] * Nn + agp[2 * k + 1];
      int rb = bgp[2 * k] * Nn + bgp[2 * k + 1];
      s += Sa[(size_t)ra * cH + h] * Sb[(size_t)rb * cH + h];
    }
    out[(size_t)loc * cH + h] = s * Se[(size_t)loc * cH + h] * mk[loc];
  }
}

__global__ __launch_bounds__(256) void att_ctx_h_k(
    const float* __restrict__ U, const float* __restrict__ V,
    const float* __restrict__ att_w, const float* __restrict__ rgh,
    const float* __restrict__ kern, const float* __restrict__ qm,
    float* __restrict__ h)
{
  int row = blockIdx.x;
  int b = row / cNR;
  __shared__ float Ur[cH];
  __shared__ float att[cNG];
  int tid = threadIdx.x;
  for (int n = tid; n < cH; n += 256) Ur[n] = U[(size_t)row * cH + n];
  __syncthreads();
  int wave = tid >> 6, lane = tid & 63;
  for (int j = wave; j < cNG; j += 4) {
    const float* Vr = V + (size_t)(b * cNG + j) * cH;
    float s = 0.f;
    for (int n = lane; n < cH; n += 64)
      s += fmaxf(Ur[n] + Vr[n], 0.f) * att_w[n];
    for (int off = 32; off; off >>= 1) s += __shfl_down(s, off);
    if (lane == 0) att[j] = 1.f / (1.f + expf(-s));
  }
  __syncthreads();
  float* hrow = h + (size_t)row * cF;
  for (int hh = tid; hh < cH; hh += 256) {
    float c = 0.f;
    for (int j = 0; j < cNG; ++j)
      c += att[j] * rgh[(size_t)(b * cNG + j) * cH + hh];
    hrow[cH + hh] = c;
  }
  for (int c0 = tid; c0 < cH; c0 += 256) hrow[c0] = kern[(size_t)row * cH + c0];
  for (int q0 = tid; q0 < cQM; q0 += 256) hrow[2 * cH + q0] = qm[(size_t)row * cQM + q0];
}

__global__ void seg_final_k(const float* __restrict__ ps,
                            const int* __restrict__ cm, float* __restrict__ out)
{
  __shared__ float s[cB];
  int tid = threadIdx.x;
  if (tid < cB) s[tid] = 0.f;
  __syncthreads();
  for (int p = tid; p < cP; p += 256) atomicAdd(&s[cm[p * 3]], ps[p]);
  __syncthreads();
  if (tid < cB) out[tid] = s[tid] * (1.f / 128.f);
}

// ---------------------------------------------------------------------------
extern "C" void kernel_launch(void* const* d_in, const int* in_sizes, int n_in,
                              void* d_out, int out_size, void* d_ws, size_t ws_size,
                              hipStream_t stream)
{
  (void)in_sizes; (void)n_in; (void)out_size; (void)ws_size;
  const float* res_atom = (const float*)d_in[0];
  const float* res_bond = (const float*)d_in[1];
  const int*   res_ag   = (const int*)d_in[2];
  const int*   res_bg   = (const int*)d_in[3];
  const int*   res_nnb  = (const int*)d_in[4];
  const float* res_mask = (const float*)d_in[5];
  const float* rg_atom  = (const float*)d_in[6];
  const float* rg_bond  = (const float*)d_in[7];
  const int*   rg_ag    = (const int*)d_in[8];
  const int*   rg_bg    = (const int*)d_in[9];
  const int*   rg_nnb   = (const int*)d_in[10];
  const float* rg_mask  = (const float*)d_in[11];
  const int*   core     = (const int*)d_in[12];
  const float* qm       = (const float*)d_in[13];
  const float* connect  = (const float*)d_in[14];
  const float* Wm[2][6];   // [side][atom,na,nb,self,U2,U1]
  for (int s = 0; s < 2; ++s)
    for (int k = 0; k < 6; ++k) Wm[s][k] = (const float*)d_in[15 + s * 6 + k];
  const float* W_att_h  = (const float*)d_in[27];
  const float* W_att_s  = (const float*)d_in[28];
  const float* W_score0 = (const float*)d_in[29];
  const float* W_score  = (const float*)d_in[30];
  float* out = (float*)d_out;

  float* ws = (float*)d_ws;
  size_t off = 0;
  auto alloc = [&](size_t nfloat) {
    float* p = ws + off;
    off += (nfloat + 63) & ~(size_t)63;
    return p;
  };
  auto allocU = [&](size_t nush) {
    return (unsigned short*)alloc((nush + 1) / 2);
  };

  float* afA_r = alloc((size_t)Mres * cH);
  float* afB_r = alloc((size_t)Mres * cH);
  float* Rb_r  = alloc((size_t)Mres * cH);
  float* Sb_r  = alloc((size_t)Mres * cH);
  float* Ra_r  = alloc((size_t)Mres * cH);
  float* nei_r = alloc((size_t)Mres * cH);
  float* kern_r= alloc((size_t)Mres * cH);
  float* afA_g = alloc((size_t)Mrg * cH);
  float* afB_g = alloc((size_t)Mrg * cH);
  float* Rb_g  = alloc((size_t)Mrg * cH);
  float* Sb_g  = alloc((size_t)Mrg * cH);
  float* Ra_g  = alloc((size_t)Mrg * cH);
  float* nei_g = alloc((size_t)Mrg * cH);
  float* kern_g= alloc((size_t)Mrg * cH);
  float* U     = alloc((size_t)Mres * cH);
  float* V     = alloc((size_t)Mrg * cH);
  float* h760  = alloc((size_t)Mres * cF);
  float* pairsum = alloc(cP);

  // transposed/split weights: [side][kind] kinds: atom,na,nb,self,u2t,u2b,u1t,u1b
  struct WT { unsigned short *h, *l; int K, Kp; const float* src; };
  auto rup32 = [](int k) { return (k + 31) & ~31; };
  WT t[2][8]; 
  for (int s = 0; s < 2; ++s) {
    const int Ks[8] = {cAF, cH, cBF, cH, cH, cBF, cH, cH};
    const float* srcs[8] = {
      Wm[s][0], Wm[s][1], Wm[s][2], Wm[s][3],
      Wm[s][4], Wm[s][4] + (size_t)cH * cH,       // U2 top / bottom
      Wm[s][5], Wm[s][5] + (size_t)cH * cH };     // U1 top / bottom
    for (int k = 0; k < 8; ++k) {
      int Kp = rup32(Ks[k]);
      t[s][k].K = Ks[k]; t[s][k].Kp = Kp; t[s][k].src = srcs[k];
      t[s][k].h = allocU((size_t)cH * Kp);
      t[s][k].l = allocU((size_t)cH * Kp);
    }
  }
  unsigned short* attT_h = allocU((size_t)cH * 320);
  unsigned short* attT_l = allocU((size_t)cH * 320);
  unsigned short* sc0T_h = allocU((size_t)cD0 * 800);
  unsigned short* sc0T_l = allocU((size_t)cD0 * 800);

  // ---- weight prep (2 launches)
  {
    PrepArgs pa{};
    for (int s = 0; s < 2; ++s)
      for (int k = 0; k < 8; ++k)
        pa.a[s * 8 + k] = {t[s][k].src, t[s][k].h, t[s][k].l, t[s][k].K, cH, t[s][k].Kp};
    dim3 grid((cH * 320 + 255) / 256, 1, 16);   // max total = 300*320
    prep_k<<<grid, dim3(256), 0, stream>>>(pa);
  }
  {
    PrepArgs pa{};
    pa.a[0] = {W_att_h,  attT_h, attT_l, cH, cH, 320};
    pa.a[1] = {W_score0, sc0T_h, sc0T_l, cD0, cD0, 800};
    dim3 grid((cD0 * 800 + 255) / 256, 1, 2);
    prep_k<<<grid, dim3(256), 0, stream>>>(pa);
  }

  dim3 blk(256);
  GArg zero{};
  auto launch = [&](GArgs6& ga, int nprob) {
    dim3 grid(5, Mres / 64, nprob);   // N=300 -> 5 col tiles; 24 row tiles
    gemm_mfma<<<grid, blk, 0, stream>>>(ga, cH);
  };

  // prologue: af0 = relu(atom@W_atom); Rb = bond@U2bot; Sb = relu(bond@W_nb)
  {
    GArgs6 ga{{
      {res_atom, nullptr, t[0][0].h, t[0][0].l, nullptr, nullptr, afA_r, Mres, cAF, 128, 0, 0, 1},
      {rg_atom,  nullptr, t[1][0].h, t[1][0].l, nullptr, nullptr, afA_g, Mrg,  cAF, 128, 0, 0, 1},
      {res_bond, nullptr, t[0][5].h, t[0][5].l, nullptr, nullptr, Rb_r,  Mres, cBF, 32,  0, 0, 0},
      {rg_bond,  nullptr, t[1][5].h, t[1][5].l, nullptr, nullptr, Rb_g,  Mrg,  cBF, 32,  0, 0, 0},
      {res_bond, nullptr, t[0][2].h, t[0][2].l, nullptr, nullptr, Sb_r,  Mres, cBF, 32,  0, 0, 1},
      {rg_bond,  nullptr, t[1][2].h, t[1][2].l, nullptr, nullptr, Sb_g,  Mrg,  cBF, 32,  0, 0, 1},
    }};
    launch(ga, 6);
  }

  float* af_r = afA_r; float* afo_r = afB_r;
  float* af_g = afA_g; float* afo_g = afB_g;
  for (int it = 0; it < cDEPTH - 1; ++it) {
    {
      GArgs6 ga{{
        {af_r, nullptr, t[0][4].h, t[0][4].l, nullptr, nullptr, Ra_r, Mres, cH, 320, 0, 0, 0},
        {af_g, nullptr, t[1][4].h, t[1][4].l, nullptr, nullptr, Ra_g, Mrg,  cH, 320, 0, 0, 0},
        zero, zero, zero, zero,
      }};
      launch(ga, 2);
    }
    nei_label2_k<<<dim3(Mres + Mrg), dim3(320), 0, stream>>>(
        Ra_r, Rb_r, res_ag, res_bg, res_nnb, nei_r,
        Ra_g, Rb_g, rg_ag, rg_bg, rg_nnb, nei_g);
    {
      GArgs6 ga{{
        {af_r, nei_r, t[0][6].h, t[0][6].l, t[0][7].h, t[0][7].l, afo_r, Mres, cH, 320, cH, 320, 1},
        {af_g, nei_g, t[1][6].h, t[1][6].l, t[1][7].h, t[1][7].l, afo_g, Mrg,  cH, 320, cH, 320, 1},
        zero, zero, zero, zero,
      }};
      launch(ga, 2);
    }
    { float* tmp = af_r; af_r = afo_r; afo_r = tmp; }
    { float* tmp = af_g; af_g = afo_g; afo_g = tmp; }
  }

  // final iter: Sa = relu(af@W_na); SelfR = relu(af@W_self)
  {
    GArgs6 ga{{
      {af_r, nullptr, t[0][1].h, t[0][1].l, nullptr, nullptr, Ra_r,  Mres, cH, 320, 0, 0, 1},
      {af_g, nullptr, t[1][1].h, t[1][1].l, nullptr, nullptr, Ra_g,  Mrg,  cH, 320, 0, 0, 1},
      {af_r, nullptr, t[0][3].h, t[0][3].l, nullptr, nullptr, nei_r, Mres, cH, 320, 0, 0, 1},
      {af_g, nullptr, t[1][3].h, t[1][3].l, nullptr, nullptr, nei_g, Mrg,  cH, 320, 0, 0, 1},
      zero, zero,
    }};
    launch(ga, 4);
  }
  kernels2_k<<<dim3(Mres + Mrg), dim3(320), 0, stream>>>(
      Ra_r, Sb_r, nei_r, res_ag, res_bg, res_nnb, res_mask, kern_r,
      Ra_g, Sb_g, nei_g, rg_ag, rg_bg, rg_nnb, rg_mask, kern_g);

  // U / V = kern @ W_att_h
  {
    GArgs6 ga{{
      {kern_r, nullptr, attT_h, attT_l, nullptr, nullptr, U, Mres, cH, 320, 0, 0, 0},
      {kern_g, nullptr, attT_h, attT_l, nullptr, nullptr, V, Mrg,  cH, 320, 0, 0, 0},
      zero, zero, zero, zero,
    }};
    launch(ga, 2);
  }
  att_ctx_h_k<<<dim3(Mres), dim3(256), 0, stream>>>(U, V, W_att_s, kern_g, kern_r, qm, h760);

  hipMemsetAsync(pairsum, 0, cP * sizeof(float), stream);
  score_mfma_k<<<dim3(13, cP / 64), blk, 0, stream>>>(
      h760, connect, core, sc0T_h, sc0T_l, W_score, pairsum);
  seg_final_k<<<dim3(1), dim3(256), 0, stream>>>(pairsum, core, out);
}

// Round 6
// 270.278 us; speedup vs baseline: 4.3341x; 1.0390x over previous
//
#include <hip/hip_runtime.h>

// ---------------------------------------------------------------------------
// QMWLNPairwiseAtomClassifier — round 6 (= round 4 + att_ctx v2 ONLY):
//  * split-bf16 MFMA GEMMs (round 4, verified passing)
//  * att_ctx v2: 4-row blocks, register U/w, 4-wide j ILP, LDS att broadcast
// ---------------------------------------------------------------------------

constexpr int cB = 16, cNR = 96, cNG = 64;
constexpr int cAF = 98, cBF = 6;
constexpr int cH = 300, cQM = 160, cMAXNB = 10, cDEPTH = 4;
constexpr int cP = 2048;
constexpr int cF = 2 * cH + cQM;   // 760
constexpr int cD0 = cF + 10;       // 770

constexpr int Mres = cB * cNR;     // 1536
constexpr int Mrg  = cB * cNG;     // 1024

typedef __attribute__((ext_vector_type(8))) short v8s;
typedef __attribute__((ext_vector_type(4))) float v4f;

__device__ inline unsigned short f2bf(float f) {
  unsigned u = __float_as_uint(f);
  u += 0x7FFF + ((u >> 16) & 1);          // RNE
  return (unsigned short)(u >> 16);
}
__device__ inline float bf2f(unsigned short s) {
  return __uint_as_float(((unsigned)s) << 16);
}

// ---------------- weight prep: W[K][N] f32 -> hiT/loT [N][Kpad] bf16 --------
struct PrepArg { const float* W; unsigned short* hiT; unsigned short* loT; int K; int N; int Kpad; };
struct PrepArgs { PrepArg a[16]; };

__global__ __launch_bounds__(256) void prep_k(PrepArgs pa)
{
  PrepArg p = pa.a[blockIdx.z];
  int idx = blockIdx.x * 256 + threadIdx.x;
  int total = p.N * p.Kpad;
  if (idx >= total) return;
  int n = idx / p.Kpad, k = idx - n * p.Kpad;
  float w = (k < p.K) ? p.W[(size_t)k * p.N + n] : 0.f;
  unsigned short h = f2bf(w);
  p.hiT[idx] = h;
  p.loT[idx] = f2bf(w - bf2f(h));
}

// ---------------- MFMA GEMM: C = act(A@W1 [+ A2@W2]) ------------------------
struct GArg {
  const float* A; const float* A2;
  const unsigned short* W1h; const unsigned short* W1l;
  const unsigned short* W2h; const unsigned short* W2l;
  float* C; int M; int K1; int Kp1; int K2; int Kp2; int act;
};
struct GArgs6 { GArg a[6]; };

#define MFMA __builtin_amdgcn_mfma_f32_16x16x32_bf16

__global__ __launch_bounds__(256) void gemm_mfma(GArgs6 ga, int N)
{
  GArg g = ga.a[blockIdx.z];
  int m0 = blockIdx.y * 64;
  if (m0 >= g.M) return;
  int n0 = blockIdx.x * 64;
  int nT = (g.Kp1 + g.Kp2) >> 5;

  __shared__ unsigned short Ah[2][64][40];   // 80B rows: 2-way-only bank alias
  __shared__ unsigned short Al[2][64][40];
  __shared__ unsigned short Bh[2][64][40];
  __shared__ unsigned short Bl[2][64][40];

  int tid = threadIdx.x;
  int sm = tid >> 2;            // staging row (A-m / B-n)
  int sk = (tid & 3) << 3;      // staging k offset (0,8,16,24)

  float areg[8];
  uint4 bh_reg, bl_reg;

  auto fetch = [&](int kv0) {
    int kv = kv0 + sk;
    const float* src; int kk, Klim;
    if (kv < g.Kp1) { src = g.A  + (size_t)(m0 + sm) * g.K1; kk = kv;          Klim = g.K1; }
    else            { src = g.A2 + (size_t)(m0 + sm) * g.K2; kk = kv - g.Kp1;  Klim = g.K2; }
    if (((Klim & 3) == 0) && kk + 7 < Klim) {
      float4 v0 = *(const float4*)(src + kk);
      float4 v1 = *(const float4*)(src + kk + 4);
      areg[0]=v0.x; areg[1]=v0.y; areg[2]=v0.z; areg[3]=v0.w;
      areg[4]=v1.x; areg[5]=v1.y; areg[6]=v1.z; areg[7]=v1.w;
    } else {
#pragma unroll
      for (int j = 0; j < 8; ++j) {
        int k = kk + j;
        areg[j] = (k < Klim) ? src[k] : 0.f;
      }
    }
    int gn = n0 + sm;
    if (gn < N) {
      const unsigned short *ph, *pl;
      if (kv < g.Kp1) { size_t o = (size_t)gn * g.Kp1 + kv;            ph = g.W1h + o; pl = g.W1l + o; }
      else            { size_t o = (size_t)gn * g.Kp2 + (kv - g.Kp1);  ph = g.W2h + o; pl = g.W2l + o; }
      bh_reg = *(const uint4*)ph;
      bl_reg = *(const uint4*)pl;
    } else {
      bh_reg = make_uint4(0,0,0,0); bl_reg = make_uint4(0,0,0,0);
    }
  };

  auto store = [&](int buf) {
    unsigned hs[8], ls[8];
#pragma unroll
    for (int j = 0; j < 8; ++j) {
      unsigned short h = f2bf(areg[j]);
      hs[j] = h;
      ls[j] = f2bf(areg[j] - bf2f(h));
    }
    uint4 hh, ll;
    hh.x = hs[0] | (hs[1] << 16); hh.y = hs[2] | (hs[3] << 16);
    hh.z = hs[4] | (hs[5] << 16); hh.w = hs[6] | (hs[7] << 16);
    ll.x = ls[0] | (ls[1] << 16); ll.y = ls[2] | (ls[3] << 16);
    ll.z = ls[4] | (ls[5] << 16); ll.w = ls[6] | (ls[7] << 16);
    *(uint4*)&Ah[buf][sm][sk] = hh;
    *(uint4*)&Al[buf][sm][sk] = ll;
    *(uint4*)&Bh[buf][sm][sk] = bh_reg;
    *(uint4*)&Bl[buf][sm][sk] = bl_reg;
  };

  int l = tid & 63, w = tid >> 6;
  int wm = (w >> 1) << 5, wn = (w & 1) << 5;     // 2x2 wave grid, 32x32 each
  int ar = wm + (l & 15), br = wn + (l & 15);
  int kc = (l >> 4) << 3;

  v4f acc00 = {0,0,0,0}, acc01 = {0,0,0,0}, acc10 = {0,0,0,0}, acc11 = {0,0,0,0};

  fetch(0); store(0); __syncthreads();
  for (int t = 0; t < nT; ++t) {
    if (t + 1 < nT) fetch((t + 1) << 5);
    int cur = t & 1;
    v8s ah0 = *(const v8s*)&Ah[cur][ar][kc];
    v8s ah1 = *(const v8s*)&Ah[cur][ar + 16][kc];
    v8s al0 = *(const v8s*)&Al[cur][ar][kc];
    v8s al1 = *(const v8s*)&Al[cur][ar + 16][kc];
    v8s bh0 = *(const v8s*)&Bh[cur][br][kc];
    v8s bh1 = *(const v8s*)&Bh[cur][br + 16][kc];
    v8s bl0 = *(const v8s*)&Bl[cur][br][kc];
    v8s bl1 = *(const v8s*)&Bl[cur][br + 16][kc];
    acc00 = MFMA(ah0, bh0, acc00, 0, 0, 0);
    acc00 = MFMA(ah0, bl0, acc00, 0, 0, 0);
    acc00 = MFMA(al0, bh0, acc00, 0, 0, 0);
    acc01 = MFMA(ah0, bh1, acc01, 0, 0, 0);
    acc01 = MFMA(ah0, bl1, acc01, 0, 0, 0);
    acc01 = MFMA(al0, bh1, acc01, 0, 0, 0);
    acc10 = MFMA(ah1, bh0, acc10, 0, 0, 0);
    acc10 = MFMA(ah1, bl0, acc10, 0, 0, 0);
    acc10 = MFMA(al1, bh0, acc10, 0, 0, 0);
    acc11 = MFMA(ah1, bh1, acc11, 0, 0, 0);
    acc11 = MFMA(ah1, bl1, acc11, 0, 0, 0);
    acc11 = MFMA(al1, bh1, acc11, 0, 0, 0);
    if (t + 1 < nT) store(cur ^ 1);
    __syncthreads();
  }

  int rbase = m0 + wm + ((l >> 4) << 2);
  int cbase = n0 + wn + (l & 15);
  auto wr = [&](v4f a, int fi, int fj) {
    int gn = cbase + fj * 16;
    if (gn >= N) return;
    float* Cp = g.C + (size_t)(rbase + fi * 16) * N + gn;
#pragma unroll
    for (int r = 0; r < 4; ++r) {
      float v = a[r];
      if (g.act) v = fmaxf(v, 0.f);
      Cp[(size_t)r * N] = v;
    }
  };
  wr(acc00, 0, 0); wr(acc01, 0, 1); wr(acc10, 1, 0); wr(acc11, 1, 1);
}

// ---------------- score GEMM (gathered A) + fused rh·Wsc segment sums -------
__global__ __launch_bounds__(256) void score_mfma_k(
    const float* __restrict__ h, const float* __restrict__ conn,
    const int* __restrict__ cm,
    const unsigned short* __restrict__ W0h, const unsigned short* __restrict__ W0l,
    const float* __restrict__ Wsc, float* __restrict__ pairsum)
{
  const int Kp = 800;               // roundup(770,32)
  const int nT = Kp >> 5;           // 25
  int m0 = blockIdx.y * 64;
  int n0 = blockIdx.x * 64;

  __shared__ unsigned short Ah[2][64][40];
  __shared__ unsigned short Al[2][64][40];
  __shared__ unsigned short Bh[2][64][40];
  __shared__ unsigned short Bl[2][64][40];

  int tid = threadIdx.x;
  int sm = tid >> 2;
  int sk = (tid & 3) << 3;

  int p = m0 + sm;
  int s3 = cm[p * 3 + 0];
  const float* h1 = h + (size_t)(s3 * cNR + cm[p * 3 + 1]) * cF;
  const float* h2 = h + (size_t)(s3 * cNR + cm[p * 3 + 2]) * cF;
  const float* cp = conn + (size_t)p * 10;

  float areg[8];
  uint4 bh_reg, bl_reg;

  auto fetch = [&](int kv0) {
    int kv = kv0 + sk;
    if (kv + 7 < cF) {
      float4 u = *(const float4*)(h1 + kv);
      float4 v = *(const float4*)(h2 + kv);
      float4 u2 = *(const float4*)(h1 + kv + 4);
      float4 v2 = *(const float4*)(h2 + kv + 4);
      areg[0]=u.x+v.x; areg[1]=u.y+v.y; areg[2]=u.z+v.z; areg[3]=u.w+v.w;
      areg[4]=u2.x+v2.x; areg[5]=u2.y+v2.y; areg[6]=u2.z+v2.z; areg[7]=u2.w+v2.w;
    } else {
#pragma unroll
      for (int j = 0; j < 8; ++j) {
        int k = kv + j;
        float v = 0.f;
        if (k < cF) v = h1[k] + h2[k];
        else if (k < cD0) v = cp[k - cF];
        areg[j] = v;
      }
    }
    int gn = n0 + sm;
    if (gn < cD0) {
      size_t o = (size_t)gn * Kp + kv;
      bh_reg = *(const uint4*)(W0h + o);
      bl_reg = *(const uint4*)(W0l + o);
    } else {
      bh_reg = make_uint4(0,0,0,0); bl_reg = make_uint4(0,0,0,0);
    }
  };

  auto store = [&](int buf) {
    unsigned hs[8], ls[8];
#pragma unroll
    for (int j = 0; j < 8; ++j) {
      unsigned short hv = f2bf(areg[j]);
      hs[j] = hv;
      ls[j] = f2bf(areg[j] - bf2f(hv));
    }
    uint4 hh, ll;
    hh.x = hs[0] | (hs[1] << 16); hh.y = hs[2] | (hs[3] << 16);
    hh.z = hs[4] | (hs[5] << 16); hh.w = hs[6] | (hs[7] << 16);
    ll.x = ls[0] | (ls[1] << 16); ll.y = ls[2] | (ls[3] << 16);
    ll.z = ls[4] | (ls[5] << 16); ll.w = ls[6] | (ls[7] << 16);
    *(uint4*)&Ah[buf][sm][sk] = hh;
    *(uint4*)&Al[buf][sm][sk] = ll;
    *(uint4*)&Bh[buf][sm][sk] = bh_reg;
    *(uint4*)&Bl[buf][sm][sk] = bl_reg;
  };

  int l = tid & 63, w = tid >> 6;
  int wm = (w >> 1) << 5, wn = (w & 1) << 5;
  int ar = wm + (l & 15), br = wn + (l & 15);
  int kc = (l >> 4) << 3;

  v4f acc00 = {0,0,0,0}, acc01 = {0,0,0,0}, acc10 = {0,0,0,0}, acc11 = {0,0,0,0};

  fetch(0); store(0); __syncthreads();
  for (int t = 0; t < nT; ++t) {
    if (t + 1 < nT) fetch((t + 1) << 5);
    int cur = t & 1;
    v8s ah0 = *(const v8s*)&Ah[cur][ar][kc];
    v8s ah1 = *(const v8s*)&Ah[cur][ar + 16][kc];
    v8s al0 = *(const v8s*)&Al[cur][ar][kc];
    v8s al1 = *(const v8s*)&Al[cur][ar + 16][kc];
    v8s bh0 = *(const v8s*)&Bh[cur][br][kc];
    v8s bh1 = *(const v8s*)&Bh[cur][br + 16][kc];
    v8s bl0 = *(const v8s*)&Bl[cur][br][kc];
    v8s bl1 = *(const v8s*)&Bl[cur][br + 16][kc];
    acc00 = MFMA(ah0, bh0, acc00, 0, 0, 0);
    acc00 = MFMA(ah0, bl0, acc00, 0, 0, 0);
    acc00 = MFMA(al0, bh0, acc00, 0, 0, 0);
    acc01 = MFMA(ah0, bh1, acc01, 0, 0, 0);
    acc01 = MFMA(ah0, bl1, acc01, 0, 0, 0);
    acc01 = MFMA(al0, bh1, acc01, 0, 0, 0);
    acc10 = MFMA(ah1, bh0, acc10, 0, 0, 0);
    acc10 = MFMA(ah1, bl0, acc10, 0, 0, 0);
    acc10 = MFMA(al1, bh0, acc10, 0, 0, 0);
    acc11 = MFMA(ah1, bh1, acc11, 0, 0, 0);
    acc11 = MFMA(ah1, bl1, acc11, 0, 0, 0);
    acc11 = MFMA(al1, bh1, acc11, 0, 0, 0);
    if (t + 1 < nT) store(cur ^ 1);
    __syncthreads();
  }

  // fused epilogue: relu + dot with W_score cols of this tile, reduce 16 lanes
  int cbase = n0 + wn + (l & 15);
  float w0 = (cbase      < cD0) ? Wsc[cbase]      : 0.f;
  float w1 = (cbase + 16 < cD0) ? Wsc[cbase + 16] : 0.f;
  float ps[8];
#pragma unroll
  for (int r = 0; r < 4; ++r) {
    ps[r]     = fmaxf(acc00[r], 0.f) * w0 + fmaxf(acc01[r], 0.f) * w1;
    ps[4 + r] = fmaxf(acc10[r], 0.f) * w0 + fmaxf(acc11[r], 0.f) * w1;
  }
#pragma unroll
  for (int m = 1; m < 16; m <<= 1) {
#pragma unroll
    for (int q = 0; q < 8; ++q) ps[q] += __shfl_xor(ps[q], m, 64);
  }
  if ((l & 15) == 0) {
#pragma unroll
    for (int q = 0; q < 8; ++q) {
      int gm = m0 + wm + (q >> 2) * 16 + ((l >> 4) << 2) + (q & 3);
      atomicAdd(&pairsum[gm], ps[q]);
    }
  }
}

// ---------------- gathers (unchanged, exact f32) ----------------------------
__global__ __launch_bounds__(320) void nei_label2_k(
    const float* __restrict__ RaR, const float* __restrict__ RbR,
    const int* __restrict__ agR, const int* __restrict__ bgR,
    const int* __restrict__ nnbR, float* __restrict__ outR,
    const float* __restrict__ RaG, const float* __restrict__ RbG,
    const int* __restrict__ agG, const int* __restrict__ bgG,
    const int* __restrict__ nnbG, float* __restrict__ outG)
{
  int node = blockIdx.x;
  const float *Ra, *Rb; const int *ag, *bg, *nnb; float* out; int Nn, loc;
  if (node < Mres) { Ra=RaR; Rb=RbR; ag=agR; bg=bgR; nnb=nnbR; out=outR; Nn=cNR; loc=node; }
  else { Ra=RaG; Rb=RbG; ag=agG; bg=bgG; nnb=nnbG; out=outG; Nn=cNG; loc=node-Mres; }
  int h = threadIdx.x;
  int nn = nnb[loc];
  const int* agp = ag + (size_t)loc * cMAXNB * 2;
  const int* bgp = bg + (size_t)loc * cMAXNB * 2;
  if (h < cH) {
    float s = 0.f;
    for (int k = 0; k < nn; ++k) {
      int ra = agp[2 * k] * Nn + agp[2 * k + 1];
      int rb = bgp[2 * k] * Nn + bgp[2 * k + 1];
      s += fmaxf(Ra[(size_t)ra * cH + h] + Rb[(size_t)rb * cH + h], 0.f);
    }
    out[(size_t)loc * cH + h] = s;
  }
}

__global__ __launch_bounds__(320) void kernels2_k(
    const float* __restrict__ SaR, const float* __restrict__ SbR,
    const float* __restrict__ SelfR_R,
    const int* __restrict__ agR, const int* __restrict__ bgR,
    const int* __restrict__ nnbR, const float* __restrict__ maskR,
    float* __restrict__ outR,
    const float* __restrict__ SaG, const float* __restrict__ SbG,
    const float* __restrict__ SelfR_G,
    const int* __restrict__ agG, const int* __restrict__ bgG,
    const int* __restrict__ nnbG, const float* __restrict__ maskG,
    float* __restrict__ outG)
{
  int node = blockIdx.x;
  const float *Sa, *Sb, *Se, *mk; const int *ag, *bg, *nnb; float* out; int Nn, loc;
  if (node < Mres) { Sa=SaR; Sb=SbR; Se=SelfR_R; ag=agR; bg=bgR; nnb=nnbR; mk=maskR; out=outR; Nn=cNR; loc=node; }
  else { Sa=SaG; Sb=SbG; Se=SelfR_G; ag=agG; bg=bgG; nnb=nnbG; mk=maskG; out=outG; Nn=cNG; loc=node-Mres; }
  int h = threadIdx.x;
  int nn = nnb[loc];
  const int* agp = ag + (size_t)loc * cMAXNB * 2;
  const int* bgp = bg + (size_t)loc * cMAXNB * 2;
  if (h < cH) {
    float s = 0.f;
    for (int k = 0; k < nn; ++k) {
      int ra = agp[2 * k] * Nn + agp[2 * k + 1];
      int rb = bgp[2 * k] * Nn + bgp[2 * k + 1];
      s += Sa[(size_t)ra * cH + h] * Sb[(size_t)rb * cH + h];
    }
    out[(size_t)loc * cH + h] = s * Se[(size_t)loc * cH + h] * mk[loc];
  }
}

// ---------------- attention + ctx + h assembly, v2 (LDS att broadcast) ------
#define AIT 4
__global__ __launch_bounds__(256) void att_ctx_h_k(
    const float* __restrict__ U, const float* __restrict__ V,
    const float* __restrict__ att_w, const float* __restrict__ rgh,
    const float* __restrict__ kern, const float* __restrict__ qm,
    float* __restrict__ h)
{
  __shared__ float attL[AIT][cNG];
  int blk = blockIdx.x;                       // 16 * 24 = 384 blocks
  int b = blk / (cNR / AIT);
  int it = blk - b * (cNR / AIT);
  int row0 = b * cNR + it * AIT;
  int tid = threadIdx.x, lane = tid & 63, w = tid >> 6;
  int n0 = lane * 4, n1 = 256 + lane * 4;
  bool v1 = (lane < 11);                      // cols 256..299 covered by lanes 0..10
  float4 z4 = make_float4(0.f, 0.f, 0.f, 0.f);

  float4 u[AIT][2], wv[2];
  wv[0] = *(const float4*)(att_w + n0);
  wv[1] = v1 ? *(const float4*)(att_w + n1) : z4;
#pragma unroll
  for (int i = 0; i < AIT; ++i) {
    const float* Ur = U + (size_t)(row0 + i) * cH;
    u[i][0] = *(const float4*)(Ur + n0);
    u[i][1] = v1 ? *(const float4*)(Ur + n1) : z4;
  }

  for (int r = 0; r < 4; ++r) {
    int jb = w * 16 + r * 4;
    float4 vv[4][2];
#pragma unroll
    for (int q = 0; q < 4; ++q) {
      const float* Vr = V + (size_t)(b * cNG + jb + q) * cH;
      vv[q][0] = *(const float4*)(Vr + n0);
      vv[q][1] = v1 ? *(const float4*)(Vr + n1) : z4;
    }
    float s[4][AIT];
#pragma unroll
    for (int q = 0; q < 4; ++q)
#pragma unroll
      for (int i = 0; i < AIT; ++i) {
        float acc = 0.f;
#pragma unroll
        for (int pp = 0; pp < 2; ++pp) {
          float4 uu = u[i][pp], vq = vv[q][pp], ww = wv[pp];
          acc += fmaxf(uu.x + vq.x, 0.f) * ww.x;
          acc += fmaxf(uu.y + vq.y, 0.f) * ww.y;
          acc += fmaxf(uu.z + vq.z, 0.f) * ww.z;
          acc += fmaxf(uu.w + vq.w, 0.f) * ww.w;
        }
        s[q][i] = acc;
      }
#pragma unroll
    for (int m = 1; m < 64; m <<= 1)
#pragma unroll
      for (int q = 0; q < 4; ++q)
#pragma unroll
        for (int i = 0; i < AIT; ++i)
          s[q][i] += __shfl_xor(s[q][i], m);
    if (lane < 16) {
      float sv = 0.f;
#pragma unroll
      for (int q = 0; q < 4; ++q)
#pragma unroll
        for (int i = 0; i < AIT; ++i)
          if (lane == q * 4 + i) sv = s[q][i];
      attL[lane & 3][jb + (lane >> 2)] = 1.f / (1.f + expf(-sv));
    }
  }
  __syncthreads();

  // ctx: wave w owns row i=w; att coefficients broadcast from LDS
  const float* rgb = rgh + (size_t)b * cNG * cH;
  float* hrow = h + (size_t)(row0 + w) * cF;
  for (int c = lane; c < 75; c += 64) {
    float4 p = z4;
    for (int j = 0; j < cNG; ++j) {
      float aj = attL[w][j];
      float4 rv = *(const float4*)(rgb + (size_t)j * cH + c * 4);
      p.x += aj * rv.x; p.y += aj * rv.y; p.z += aj * rv.z; p.w += aj * rv.w;
    }
    *(float4*)(hrow + cH + c * 4) = p;
  }
  // copy kern / qm segments of h
  for (int idx = tid; idx < AIT * 75; idx += 256) {
    int i = idx / 75, c = idx - i * 75;
    *(float4*)(h + (size_t)(row0 + i) * cF + c * 4) =
        *(const float4*)(kern + (size_t)(row0 + i) * cH + c * 4);
  }
  for (int idx = tid; idx < AIT * 40; idx += 256) {
    int i = idx / 40, c = idx - i * 40;
    *(float4*)(h + (size_t)(row0 + i) * cF + 2 * cH + c * 4) =
        *(const float4*)(qm + (size_t)(row0 + i) * cQM + c * 4);
  }
}

__global__ void seg_final_k(const float* __restrict__ ps,
                            const int* __restrict__ cm, float* __restrict__ out)
{
  __shared__ float s[cB];
  int tid = threadIdx.x;
  if (tid < cB) s[tid] = 0.f;
  __syncthreads();
  for (int p = tid; p < cP; p += 256) atomicAdd(&s[cm[p * 3]], ps[p]);
  __syncthreads();
  if (tid < cB) out[tid] = s[tid] * (1.f / 128.f);
}

// ---------------------------------------------------------------------------
extern "C" void kernel_launch(void* const* d_in, const int* in_sizes, int n_in,
                              void* d_out, int out_size, void* d_ws, size_t ws_size,
                              hipStream_t stream)
{
  (void)in_sizes; (void)n_in; (void)out_size; (void)ws_size;
  const float* res_atom = (const float*)d_in[0];
  const float* res_bond = (const float*)d_in[1];
  const int*   res_ag   = (const int*)d_in[2];
  const int*   res_bg   = (const int*)d_in[3];
  const int*   res_nnb  = (const int*)d_in[4];
  const float* res_mask = (const float*)d_in[5];
  const float* rg_atom  = (const float*)d_in[6];
  const float* rg_bond  = (const float*)d_in[7];
  const int*   rg_ag    = (const int*)d_in[8];
  const int*   rg_bg    = (const int*)d_in[9];
  const int*   rg_nnb   = (const int*)d_in[10];
  const float* rg_mask  = (const float*)d_in[11];
  const int*   core     = (const int*)d_in[12];
  const float* qm       = (const float*)d_in[13];
  const float* connect  = (const float*)d_in[14];
  const float* Wm[2][6];   // [side][atom,na,nb,self,U2,U1]
  for (int s = 0; s < 2; ++s)
    for (int k = 0; k < 6; ++k) Wm[s][k] = (const float*)d_in[15 + s * 6 + k];
  const float* W_att_h  = (const float*)d_in[27];
  const float* W_att_s  = (const float*)d_in[28];
  const float* W_score0 = (const float*)d_in[29];
  const float* W_score  = (const float*)d_in[30];
  float* out = (float*)d_out;

  float* ws = (float*)d_ws;
  size_t off = 0;
  auto alloc = [&](size_t nfloat) {
    float* p = ws + off;
    off += (nfloat + 63) & ~(size_t)63;
    return p;
  };
  auto allocU = [&](size_t nush) {
    return (unsigned short*)alloc((nush + 1) / 2);
  };

  float* afA_r = alloc((size_t)Mres * cH);
  float* afB_r = alloc((size_t)Mres * cH);
  float* Rb_r  = alloc((size_t)Mres * cH);
  float* Sb_r  = alloc((size_t)Mres * cH);
  float* Ra_r  = alloc((size_t)Mres * cH);
  float* nei_r = alloc((size_t)Mres * cH);
  float* kern_r= alloc((size_t)Mres * cH);
  float* afA_g = alloc((size_t)Mrg * cH);
  float* afB_g = alloc((size_t)Mrg * cH);
  float* Rb_g  = alloc((size_t)Mrg * cH);
  float* Sb_g  = alloc((size_t)Mrg * cH);
  float* Ra_g  = alloc((size_t)Mrg * cH);
  float* nei_g = alloc((size_t)Mrg * cH);
  float* kern_g= alloc((size_t)Mrg * cH);
  float* U     = alloc((size_t)Mres * cH);
  float* V     = alloc((size_t)Mrg * cH);
  float* h760  = alloc((size_t)Mres * cF);
  float* pairsum = alloc(cP);

  // transposed/split weights: [side][kind] kinds: atom,na,nb,self,u2t,u2b,u1t,u1b
  struct WT { unsigned short *h, *l; int K, Kp; const float* src; };
  auto rup32 = [](int k) { return (k + 31) & ~31; };
  WT t[2][8];
  for (int s = 0; s < 2; ++s) {
    const int Ks[8] = {cAF, cH, cBF, cH, cH, cBF, cH, cH};
    const float* srcs[8] = {
      Wm[s][0], Wm[s][1], Wm[s][2], Wm[s][3],
      Wm[s][4], Wm[s][4] + (size_t)cH * cH,       // U2 top / bottom
      Wm[s][5], Wm[s][5] + (size_t)cH * cH };     // U1 top / bottom
    for (int k = 0; k < 8; ++k) {
      int Kp = rup32(Ks[k]);
      t[s][k].K = Ks[k]; t[s][k].Kp = Kp; t[s][k].src = srcs[k];
      t[s][k].h = allocU((size_t)cH * Kp);
      t[s][k].l = allocU((size_t)cH * Kp);
    }
  }
  unsigned short* attT_h = allocU((size_t)cH * 320);
  unsigned short* attT_l = allocU((size_t)cH * 320);
  unsigned short* sc0T_h = allocU((size_t)cD0 * 800);
  unsigned short* sc0T_l = allocU((size_t)cD0 * 800);

  // ---- weight prep (2 launches)
  {
    PrepArgs pa{};
    for (int s = 0; s < 2; ++s)
      for (int k = 0; k < 8; ++k)
        pa.a[s * 8 + k] = {t[s][k].src, t[s][k].h, t[s][k].l, t[s][k].K, cH, t[s][k].Kp};
    dim3 grid((cH * 320 + 255) / 256, 1, 16);   // max total = 300*320
    prep_k<<<grid, dim3(256), 0, stream>>>(pa);
  }
  {
    PrepArgs pa{};
    pa.a[0] = {W_att_h,  attT_h, attT_l, cH, cH, 320};
    pa.a[1] = {W_score0, sc0T_h, sc0T_l, cD0, cD0, 800};
    dim3 grid((cD0 * 800 + 255) / 256, 1, 2);
    prep_k<<<grid, dim3(256), 0, stream>>>(pa);
  }

  dim3 blk(256);
  GArg zero{};
  auto launch = [&](GArgs6& ga, int nprob) {
    dim3 grid(5, Mres / 64, nprob);   // N=300 -> 5 col tiles; 24 row tiles
    gemm_mfma<<<grid, blk, 0, stream>>>(ga, cH);
  };

  // prologue: af0 = relu(atom@W_atom); Rb = bond@U2bot; Sb = relu(bond@W_nb)
  {
    GArgs6 ga{{
      {res_atom, nullptr, t[0][0].h, t[0][0].l, nullptr, nullptr, afA_r, Mres, cAF, 128, 0, 0, 1},
      {rg_atom,  nullptr, t[1][0].h, t[1][0].l, nullptr, nullptr, afA_g, Mrg,  cAF, 128, 0, 0, 1},
      {res_bond, nullptr, t[0][5].h, t[0][5].l, nullptr, nullptr, Rb_r,  Mres, cBF, 32,  0, 0, 0},
      {rg_bond,  nullptr, t[1][5].h, t[1][5].l, nullptr, nullptr, Rb_g,  Mrg,  cBF, 32,  0, 0, 0},
      {res_bond, nullptr, t[0][2].h, t[0][2].l, nullptr, nullptr, Sb_r,  Mres, cBF, 32,  0, 0, 1},
      {rg_bond,  nullptr, t[1][2].h, t[1][2].l, nullptr, nullptr, Sb_g,  Mrg,  cBF, 32,  0, 0, 1},
    }};
    launch(ga, 6);
  }

  float* af_r = afA_r; float* afo_r = afB_r;
  float* af_g = afA_g; float* afo_g = afB_g;
  for (int it = 0; it < cDEPTH - 1; ++it) {
    {
      GArgs6 ga{{
        {af_r, nullptr, t[0][4].h, t[0][4].l, nullptr, nullptr, Ra_r, Mres, cH, 320, 0, 0, 0},
        {af_g, nullptr, t[1][4].h, t[1][4].l, nullptr, nullptr, Ra_g, Mrg,  cH, 320, 0, 0, 0},
        zero, zero, zero, zero,
      }};
      launch(ga, 2);
    }
    nei_label2_k<<<dim3(Mres + Mrg), dim3(320), 0, stream>>>(
        Ra_r, Rb_r, res_ag, res_bg, res_nnb, nei_r,
        Ra_g, Rb_g, rg_ag, rg_bg, rg_nnb, nei_g);
    {
      GArgs6 ga{{
        {af_r, nei_r, t[0][6].h, t[0][6].l, t[0][7].h, t[0][7].l, afo_r, Mres, cH, 320, cH, 320, 1},
        {af_g, nei_g, t[1][6].h, t[1][6].l, t[1][7].h, t[1][7].l, afo_g, Mrg,  cH, 320, cH, 320, 1},
        zero, zero, zero, zero,
      }};
      launch(ga, 2);
    }
    { float* tmp = af_r; af_r = afo_r; afo_r = tmp; }
    { float* tmp = af_g; af_g = afo_g; afo_g = tmp; }
  }

  // final iter: Sa = relu(af@W_na); SelfR = relu(af@W_self)
  {
    GArgs6 ga{{
      {af_r, nullptr, t[0][1].h, t[0][1].l, nullptr, nullptr, Ra_r,  Mres, cH, 320, 0, 0, 1},
      {af_g, nullptr, t[1][1].h, t[1][1].l, nullptr, nullptr, Ra_g,  Mrg,  cH, 320, 0, 0, 1},
      {af_r, nullptr, t[0][3].h, t[0][3].l, nullptr, nullptr, nei_r, Mres, cH, 320, 0, 0, 1},
      {af_g, nullptr, t[1][3].h, t[1][3].l, nullptr, nullptr, nei_g, Mrg,  cH, 320, 0, 0, 1},
      zero, zero,
    }};
    launch(ga, 4);
  }
  kernels2_k<<<dim3(Mres + Mrg), dim3(320), 0, stream>>>(
      Ra_r, Sb_r, nei_r, res_ag, res_bg, res_nnb, res_mask, kern_r,
      Ra_g, Sb_g, nei_g, rg_ag, rg_bg, rg_nnb, rg_mask, kern_g);

  // U / V = kern @ W_att_h
  {
    GArgs6 ga{{
      {kern_r, nullptr, attT_h, attT_l, nullptr, nullptr, U, Mres, cH, 320, 0, 0, 0},
      {kern_g, nullptr, attT_h, attT_l, nullptr, nullptr, V, Mrg,  cH, 320, 0, 0, 0},
      zero, zero, zero, zero,
    }};
    launch(ga, 2);
  }
  att_ctx_h_k<<<dim3(cB * (cNR / AIT)), dim3(256), 0, stream>>>(
      U, V, W_att_s, kern_g, kern_r, qm, h760);

  hipMemsetAsync(pairsum, 0, cP * sizeof(float), stream);
  score_mfma_k<<<dim3(13, cP / 64), blk, 0, stream>>>(
      h760, connect, core, sc0T_h, sc0T_l, W_score, pairsum);
  seg_final_k<<<dim3(1), dim3(256), 0, stream>>>(pairsum, core, out);
}